// Round 11
// baseline (1479.816 us; speedup 1.0000x reference)
//
#include <hip/hip_runtime.h>
#include <math.h>

typedef _Float16 f16;
typedef _Float16 h8 __attribute__((ext_vector_type(8)));
typedef _Float16 h4 __attribute__((ext_vector_type(4)));
typedef float f32x4 __attribute__((ext_vector_type(4)));

#define HEADS 12
#define DH 64
#define DD 768
#define FFD 3072
#define EMBD 300
#define KPAD 384
#define NLAYER 4
#define NB 16
#define NCTX 4096           // 16 * 256
#define NALL 6144           // 16*256 + 16*128

// ---------------- block reductions ----------------
__device__ __forceinline__ float block_reduce_sum(float v, float* red) {
  #pragma unroll
  for (int o = 32; o; o >>= 1) v += __shfl_xor(v, o);
  const int wid = threadIdx.x >> 6;
  __syncthreads();
  if ((threadIdx.x & 63) == 0) red[wid] = v;
  __syncthreads();
  float r = red[0];
  #pragma unroll
  for (int w = 1; w < 4; ++w) r += red[w];
  return r;
}

__device__ __forceinline__ float block_reduce_sum3(float v, float* red) {
  #pragma unroll
  for (int o = 32; o; o >>= 1) v += __shfl_xor(v, o);
  const int wid = threadIdx.x >> 6;
  __syncthreads();
  if ((threadIdx.x & 63) == 0) red[wid] = v;
  __syncthreads();
  return red[0] + red[1] + red[2];
}

// ---------------- async global->LDS 16B ----------------
__device__ __forceinline__ void gload16(const f16* g, f16* lds) {
  __builtin_amdgcn_global_load_lds(
      (const __attribute__((address_space(1))) unsigned int*)g,
      (__attribute__((address_space(3))) unsigned int*)lds, 16, 0, 0);
}

// ---------------- weight transpose + cast (z-batched) ----------------
__launch_bounds__(256)
__global__ void transpose_cast_kernel(const float* __restrict__ W, f16* __restrict__ Wt,
                                      int K, int M, int Kpad,
                                      size_t srcStride, size_t dstStride) {
  W += (size_t)blockIdx.z * srcStride;
  Wt += (size_t)blockIdx.z * dstStride;
  __shared__ float t[32][33];
  const int k0 = blockIdx.x * 32, m0 = blockIdx.y * 32;
  const int c = threadIdx.x & 31, r8 = threadIdx.x >> 5;
  #pragma unroll
  for (int p = 0; p < 4; ++p) {
    const int k = k0 + r8 + p * 8;
    t[r8 + p * 8][c] = (k < K && m0 + c < M) ? W[(size_t)k * M + m0 + c] : 0.f;
  }
  __syncthreads();
  #pragma unroll
  for (int p = 0; p < 4; ++p) {
    const int m = m0 + r8 + p * 8;
    const int k = k0 + c;
    if (m < M && k < Kpad) Wt[(size_t)m * Kpad + k] = (f16)t[c][r8 + p * 8];
  }
}

__launch_bounds__(256)
__global__ void castpad_kernel(const float* __restrict__ ctx, const float* __restrict__ asp,
                               f16* __restrict__ xp) {
  const int tok = blockIdx.x;
  const float* src;
  int r;
  if (tok < NCTX) { src = ctx; r = tok; } else { src = asp; r = tok - NCTX; }
  for (int j = threadIdx.x; j < KPAD; j += 256)
    xp[(size_t)tok * KPAD + j] = (j < EMBD) ? (f16)src[(size_t)r * EMBD + j] : (f16)0.f;
}

__launch_bounds__(256)
__global__ void bias_concat_kernel(const float* __restrict__ bq, const float* __restrict__ bk,
                                   const float* __restrict__ bv, float* __restrict__ bqkv) {
  const int l = blockIdx.x;
  for (int j = threadIdx.x; j < DD; j += 256) {
    bqkv[l * 3 * DD + j] = bq[l * DD + j];
    bqkv[l * 3 * DD + DD + j] = bk[l * DD + j];
    bqkv[l * 3 * DD + 2 * DD + j] = bv[l * DD + j];
  }
}

// ---------------- f16 MFMA GEMM: 3-buffer 2-ahead pipeline (R7 best) ----------
#define GBM 128
#define GBN 128
#define GBK 32

template<int K, int KSPLIT, int ACT>
__launch_bounds__(256)
__global__ void gemm_3buf(const f16* __restrict__ A, const f16* __restrict__ Bt,
                          const float* __restrict__ bias, f16* __restrict__ C, int M) {
  constexpr int KB = K / KSPLIT;
  constexpr int NSTEP = KB / GBK;
  __shared__ __align__(16) f16 As[3][GBM * GBK];
  __shared__ __align__(16) f16 Bs[3][GBN * GBK];
  const int tid = threadIdx.x, lane = tid & 63, wid = tid >> 6;
  const int wr = (wid >> 1) * 64, wc = (wid & 1) * 64;
  const int l15 = lane & 15, lg = lane >> 4;

  const int bm = blockIdx.x * GBM;
  const int bn = blockIdx.y * GBN;
  const int kb0 = (KSPLIT > 1) ? blockIdx.z * KB : 0;

  const f16* Ag[2]; const f16* Bg[2];
  int ldsOff[2];
  #pragma unroll
  for (int c = 0; c < 2; ++c) {
    const int v = c * 256 + tid;
    const int row = v >> 2, s = v & 3;
    const int gcol = (s ^ ((row >> 1) & 3)) * 8;
    Ag[c] = A + (size_t)(bm + row) * K + kb0 + gcol;
    Bg[c] = Bt + (size_t)(bn + row) * K + kb0 + gcol;
    ldsOff[c] = (c * 256 + wid * 64) * 8;
  }

  f32x4 acc[4][4] = {};

  #pragma unroll
  for (int c = 0; c < 2; ++c) {
    gload16(Ag[c], &As[0][ldsOff[c]]);
    gload16(Bg[c], &Bs[0][ldsOff[c]]);
  }
  #pragma unroll
  for (int c = 0; c < 2; ++c) {
    gload16(Ag[c] + GBK, &As[1][ldsOff[c]]);
    gload16(Bg[c] + GBK, &Bs[1][ldsOff[c]]);
  }

  int s3 = 0;
  for (int t = 0; t < NSTEP; ++t) {
    if (t + 1 < NSTEP) asm volatile("s_waitcnt vmcnt(4)" ::: "memory");
    else               asm volatile("s_waitcnt vmcnt(0)" ::: "memory");
    __builtin_amdgcn_s_barrier();
    if (t + 2 < NSTEP) {
      const int sn = (s3 + 2 >= 3) ? s3 - 1 : s3 + 2;
      const int kb = (t + 2) * GBK;
      #pragma unroll
      for (int c = 0; c < 2; ++c) {
        gload16(Ag[c] + kb, &As[sn][ldsOff[c]]);
        gload16(Bg[c] + kb, &Bs[sn][ldsOff[c]]);
      }
    }
    h8 af[4], bf[4];
    #pragma unroll
    for (int m = 0; m < 4; ++m) {
      const int row = wr + m * 16 + l15;
      af[m] = *(const h8*)&As[s3][(row * 4 + (lg ^ ((row >> 1) & 3))) * 8];
    }
    #pragma unroll
    for (int n = 0; n < 4; ++n) {
      const int row = wc + n * 16 + l15;
      bf[n] = *(const h8*)&Bs[s3][(row * 4 + (lg ^ ((row >> 1) & 3))) * 8];
    }
    #pragma unroll
    for (int m = 0; m < 4; ++m)
      #pragma unroll
      for (int n = 0; n < 4; ++n)
        acc[m][n] = __builtin_amdgcn_mfma_f32_16x16x32_f16(af[m], bf[n], acc[m][n], 0, 0, 0);
    s3 = (s3 + 1 >= 3) ? 0 : s3 + 1;
  }

  f16* Co = C + ((KSPLIT > 1) ? (size_t)blockIdx.z * NALL * M : (size_t)0);
  #pragma unroll
  for (int m = 0; m < 4; ++m) {
    #pragma unroll
    for (int n = 0; n < 4; ++n) {
      #pragma unroll
      for (int r = 0; r < 4; ++r) {
        const int row = bm + wr + m * 16 + lg * 4 + r;
        const int col = bn + wc + n * 16 + l15;
        float v = acc[m][n][r];
        if (KSPLIT == 1 || blockIdx.z == 0) v += bias[col];
        if (ACT == 1) {
          const float u = 1.5957691216057308f * (v + 0.044715f * v * v * v);
          v = v / (1.f + __expf(-u));
        }
        Co[(size_t)row * M + col] = (f16)v;
      }
    }
  }
}

// ============== ABLATION PROBES (write scratch only; FF1 shape K=768) ==============
// V0 full | V1 no C-store | V2 no global staging | V3 no ds_read (MFMA floor).
template<int V>
__launch_bounds__(256)
__global__ void gemm_probe(const f16* __restrict__ A, const f16* __restrict__ Bt,
                           const float* __restrict__ bias, f16* __restrict__ C, int M) {
  constexpr int K = 768;
  constexpr int NSTEP = 24;
  __shared__ __align__(16) f16 As[3][GBM * GBK];
  __shared__ __align__(16) f16 Bs[3][GBM * GBK];
  const int tid = threadIdx.x, lane = tid & 63, wid = tid >> 6;
  const int wr = (wid >> 1) * 64, wc = (wid & 1) * 64;
  const int l15 = lane & 15, lg = lane >> 4;
  const int bm = blockIdx.x * GBM;
  const int bn = blockIdx.y * GBN;

  const f16* Ag[2]; const f16* Bg[2];
  int ldsOff[2];
  #pragma unroll
  for (int c = 0; c < 2; ++c) {
    const int v = c * 256 + tid;
    const int row = v >> 2, s = v & 3;
    const int gcol = (s ^ ((row >> 1) & 3)) * 8;
    Ag[c] = A + (size_t)(bm + row) * K + gcol;
    Bg[c] = Bt + (size_t)(bn + row) * K + gcol;
    ldsOff[c] = (c * 256 + wid * 64) * 8;
  }

  f32x4 acc[4][4] = {};

  // prologue
  #pragma unroll
  for (int c = 0; c < 2; ++c) {
    gload16(Ag[c], &As[0][ldsOff[c]]);
    gload16(Bg[c], &Bs[0][ldsOff[c]]);
  }
  if (V <= 1) {
    #pragma unroll
    for (int c = 0; c < 2; ++c) {
      gload16(Ag[c] + GBK, &As[1][ldsOff[c]]);
      gload16(Bg[c] + GBK, &Bs[1][ldsOff[c]]);
    }
  } else {
    asm volatile("s_waitcnt vmcnt(0)" ::: "memory");
    __builtin_amdgcn_s_barrier();
  }

  h8 pf[8];   // V3 pre-loaded fragments
  if (V == 3) {
    #pragma unroll
    for (int m = 0; m < 4; ++m) {
      const int row = wr + m * 16 + l15;
      pf[m] = *(const h8*)&As[0][(row * 4 + (lg ^ ((row >> 1) & 3))) * 8];
    }
    #pragma unroll
    for (int n = 0; n < 4; ++n) {
      const int row = wc + n * 16 + l15;
      pf[4 + n] = *(const h8*)&Bs[0][(row * 4 + (lg ^ ((row >> 1) & 3))) * 8];
    }
  }

  int s3 = 0;
  for (int t = 0; t < NSTEP; ++t) {
    if (V <= 1) {
      if (t + 1 < NSTEP) asm volatile("s_waitcnt vmcnt(4)" ::: "memory");
      else               asm volatile("s_waitcnt vmcnt(0)" ::: "memory");
    }
    __builtin_amdgcn_s_barrier();
    if (V <= 1 && t + 2 < NSTEP) {
      const int sn = (s3 + 2 >= 3) ? s3 - 1 : s3 + 2;
      const int kb = (t + 2) * GBK;
      #pragma unroll
      for (int c = 0; c < 2; ++c) {
        gload16(Ag[c] + kb, &As[sn][ldsOff[c]]);
        gload16(Bg[c] + kb, &Bs[sn][ldsOff[c]]);
      }
    }
    h8 af[4], bf[4];
    if (V <= 2) {
      asm volatile("" ::: "memory");   // pin per-iter ds_reads (V2 has no LDS writes)
      #pragma unroll
      for (int m = 0; m < 4; ++m) {
        const int row = wr + m * 16 + l15;
        af[m] = *(const h8*)&As[s3][(row * 4 + (lg ^ ((row >> 1) & 3))) * 8];
      }
      #pragma unroll
      for (int n = 0; n < 4; ++n) {
        const int row = wc + n * 16 + l15;
        bf[n] = *(const h8*)&Bs[s3][(row * 4 + (lg ^ ((row >> 1) & 3))) * 8];
      }
    } else {
      #pragma unroll
      for (int m = 0; m < 4; ++m) { af[m] = pf[m]; bf[m] = pf[4 + m]; }
    }
    #pragma unroll
    for (int m = 0; m < 4; ++m)
      #pragma unroll
      for (int n = 0; n < 4; ++n)
        acc[m][n] = __builtin_amdgcn_mfma_f32_16x16x32_f16(af[m], bf[n], acc[m][n], 0, 0, 0);
    s3 = (s3 + 1 >= 3) ? 0 : s3 + 1;
  }

  if (V == 0) {
    #pragma unroll
    for (int m = 0; m < 4; ++m) {
      #pragma unroll
      for (int n = 0; n < 4; ++n) {
        #pragma unroll
        for (int r = 0; r < 4; ++r) {
          const int row = bm + wr + m * 16 + lg * 4 + r;
          const int col = bn + wc + n * 16 + l15;
          float v = acc[m][n][r] + bias[col];
          const float u = 1.5957691216057308f * (v + 0.044715f * v * v * v);
          v = v / (1.f + __expf(-u));
          C[(size_t)row * M + col] = (f16)v;
        }
      }
    }
  } else {
    #pragma unroll
    for (int m = 0; m < 4; ++m)
      #pragma unroll
      for (int n = 0; n < 4; ++n)
        asm volatile("" :: "v"(acc[m][n][0]), "v"(acc[m][n][1]),
                           "v"(acc[m][n][2]), "v"(acc[m][n][3]));
  }
}

// ---------------- MFMA attention: one block per (b,h) (R7) ----------------
template<int S>
__launch_bounds__(256)
__global__ void attn_mfma_kernel(const f16* __restrict__ qkv, f16* __restrict__ ao, int tokoff) {
  constexpr int KSTR = 88;
  constexpr int VSTR = 264;
  __shared__ __align__(16) f16 Ks[S][KSTR];
  __shared__ __align__(16) f16 Vt[DH][VSTR];
  __shared__ __align__(16) f16 Pl[4][16][VSTR];
  const int b = blockIdx.x / HEADS, h = blockIdx.x % HEADS;
  const int tid = threadIdx.x, lane = tid & 63, wid = tid >> 6;
  const int l15 = lane & 15, lg = lane >> 4;
  const size_t base = (size_t)(tokoff + b * S) * (3 * DD) + (size_t)h * DH;
  const f16* qg = qkv + base;
  const f16* kg = qkv + base + DD;
  const f16* vg = qkv + base + 2 * DD;

  for (int c = tid; c < S * 8; c += 256) {
    const int row = c >> 3, off = (c & 7) * 8;
    *(h8*)&Ks[row][off] = *(const h8*)&kg[(size_t)row * (3 * DD) + off];
    const h8 vv = *(const h8*)&vg[(size_t)row * (3 * DD) + off];
    #pragma unroll
    for (int j = 0; j < 8; ++j) Vt[off + j][row] = vv[j];
  }
  __syncthreads();

  for (int qt = wid; qt < S / 16; qt += 4) {
    const int q0 = qt * 16;
    h8 aq[2];
    #pragma unroll
    for (int s = 0; s < 2; ++s)
      aq[s] = *(const h8*)&qg[(size_t)(q0 + l15) * (3 * DD) + s * 32 + lg * 8];

    f32x4 sc[S / 16];
    #pragma unroll
    for (int kt = 0; kt < S / 16; ++kt) {
      f32x4 c = {};
      const h8 b0 = *(const h8*)&Ks[kt * 16 + l15][lg * 8];
      const h8 b1 = *(const h8*)&Ks[kt * 16 + l15][32 + lg * 8];
      c = __builtin_amdgcn_mfma_f32_16x16x32_f16(aq[0], b0, c, 0, 0, 0);
      c = __builtin_amdgcn_mfma_f32_16x16x32_f16(aq[1], b1, c, 0, 0, 0);
      sc[kt] = c;
    }
    float mx[4], zz[4];
    #pragma unroll
    for (int r = 0; r < 4; ++r) {
      float m = -1e30f;
      #pragma unroll
      for (int kt = 0; kt < S / 16; ++kt) m = fmaxf(m, sc[kt][r]);
      #pragma unroll
      for (int o = 1; o < 16; o <<= 1) m = fmaxf(m, __shfl_xor(m, o));
      mx[r] = m; zz[r] = 0.f;
    }
    #pragma unroll
    for (int kt = 0; kt < S / 16; ++kt)
      #pragma unroll
      for (int r = 0; r < 4; ++r) {
        const float p = __expf((sc[kt][r] - mx[r]) * 0.125f);
        zz[r] += p;
        Pl[wid][lg * 4 + r][kt * 16 + l15] = (f16)p;
      }
    #pragma unroll
    for (int r = 0; r < 4; ++r) {
      #pragma unroll
      for (int o = 1; o < 16; o <<= 1) zz[r] += __shfl_xor(zz[r], o);
      zz[r] = 1.f / zz[r];
    }
    f32x4 o4[4] = {};
    #pragma unroll
    for (int ks = 0; ks < S / 32; ++ks) {
      const h8 pa = *(const h8*)&Pl[wid][l15][ks * 32 + lg * 8];
      #pragma unroll
      for (int n = 0; n < 4; ++n) {
        const h8 bv_ = *(const h8*)&Vt[n * 16 + l15][ks * 32 + lg * 8];
        o4[n] = __builtin_amdgcn_mfma_f32_16x16x32_f16(pa, bv_, o4[n], 0, 0, 0);
      }
    }
    #pragma unroll
    for (int n = 0; n < 4; ++n)
      #pragma unroll
      for (int r = 0; r < 4; ++r) {
        const int row = q0 + lg * 4 + r;
        ao[(size_t)(tokoff + b * S + row) * DD + h * DH + n * 16 + l15] = (f16)(o4[n][r] * zz[r]);
      }
  }
}

// ---------------- vectorized LN kernels (192 threads, h4 = 8B/lane) ----------------
__launch_bounds__(192)
__global__ void pos_ln16v(const f16* __restrict__ tmp, const float* __restrict__ pos,
                          const float* __restrict__ g, const float* __restrict__ be,
                          f16* __restrict__ out) {
  __shared__ float red[3];
  const int tok = blockIdx.x;
  const int s = (tok < NCTX) ? (tok & 255) : (tok & 127);
  const size_t row = (size_t)tok * DD;
  const int j = threadIdx.x * 4;
  const h4 a = *(const h4*)&tmp[row + j];
  const float4 p = *(const float4*)&pos[(size_t)s * DD + j];
  float x[4] = { (float)a[0] + p.x, (float)a[1] + p.y, (float)a[2] + p.z, (float)a[3] + p.w };
  float sm = 0.f, ss = 0.f;
  #pragma unroll
  for (int i = 0; i < 4; ++i) { sm += x[i]; ss += x[i] * x[i]; }
  sm = block_reduce_sum3(sm, red);
  ss = block_reduce_sum3(ss, red);
  const float mean = sm * (1.f / DD);
  const float inv = rsqrtf(ss * (1.f / DD) - mean * mean + 1e-12f);
  const float4 gv = *(const float4*)&g[j];
  const float4 bv = *(const float4*)&be[j];
  h4 o;
  o[0] = (f16)((x[0] - mean) * inv * gv.x + bv.x);
  o[1] = (f16)((x[1] - mean) * inv * gv.y + bv.y);
  o[2] = (f16)((x[2] - mean) * inv * gv.z + bv.z);
  o[3] = (f16)((x[3] - mean) * inv * gv.w + bv.w);
  *(h4*)&out[row + j] = o;
}

template<int ND>
__launch_bounds__(192)
__global__ void add_ln16v(const f16* __restrict__ hin, const f16* __restrict__ d0,
                          const f16* __restrict__ d1,
                          const float* __restrict__ g, const float* __restrict__ be,
                          f16* __restrict__ out) {
  __shared__ float red[3];
  const size_t row = (size_t)blockIdx.x * DD;
  const int j = threadIdx.x * 4;
  const h4 a = *(const h4*)&hin[row + j];
  const h4 b = *(const h4*)&d0[row + j];
  h4 c = {};
  if (ND == 2) c = *(const h4*)&d1[row + j];
  float x[4]; float sm = 0.f, ss = 0.f;
  #pragma unroll
  for (int i = 0; i < 4; ++i) {
    float v = (float)a[i] + (float)b[i];
    if (ND == 2) v += (float)c[i];
    x[i] = v; sm += v; ss += v * v;
  }
  sm = block_reduce_sum3(sm, red);
  ss = block_reduce_sum3(ss, red);
  const float mean = sm * (1.f / DD);
  const float inv = rsqrtf(ss * (1.f / DD) - mean * mean + 1e-12f);
  const float4 gv = *(const float4*)&g[j];
  const float4 bv = *(const float4*)&be[j];
  h4 o;
  o[0] = (f16)((x[0] - mean) * inv * gv.x + bv.x);
  o[1] = (f16)((x[1] - mean) * inv * gv.y + bv.y);
  o[2] = (f16)((x[2] - mean) * inv * gv.z + bv.z);
  o[3] = (f16)((x[3] - mean) * inv * gv.w + bv.w);
  *(h4*)&out[row + j] = o;
}

// ---------------- final cosine reduction ----------------
struct OutsF16 { const f16* p[4]; };

__launch_bounds__(256)
__global__ void invnorm16_kernel(OutsF16 o4, float* __restrict__ invn) {
  __shared__ float red[4];
  const size_t row = (size_t)blockIdx.x * DD;
  float ss = 0.f;
  #pragma unroll
  for (int l = 0; l < 4; ++l)
    #pragma unroll
    for (int i = 0; i < 3; ++i) {
      const float v = (float)o4.p[l][row + threadIdx.x + (i << 8)];
      ss += v * v;
    }
  ss = block_reduce_sum(ss, red);
  if (threadIdx.x == 0) invn[blockIdx.x] = 1.f / fmaxf(sqrtf(ss), 1e-8f);
}

__launch_bounds__(256)
__global__ void normsum16_kernel(OutsF16 o4, const float* __restrict__ invn,
                                 float* __restrict__ accC, float* __restrict__ accA) {
  const int b = blockIdx.x;
  const int l = blockIdx.y / 3;
  const int j = (blockIdx.y % 3) * 256 + threadIdx.x;
  const int pass = blockIdx.z;
  const int S = pass ? 128 : 256;
  const int tb = pass ? (NCTX + b * 128) : (b * 256);
  float* acc = pass ? accA : accC;
  const f16* __restrict__ src = o4.p[l];
  float s = 0.f;
  for (int si = 0; si < S; ++si)
    s = fmaf((float)src[(size_t)(tb + si) * DD + j], invn[tb + si], s);
  acc[(size_t)b * (4 * DD) + (size_t)l * DD + j] = s;
}

__launch_bounds__(256)
__global__ void final_dot_kernel(const float* __restrict__ a, const float* __restrict__ c,
                                 float* __restrict__ out) {
  __shared__ float red[4];
  const size_t base = (size_t)blockIdx.x * (4 * DD);
  float s = 0.f;
  #pragma unroll
  for (int i = 0; i < 12; ++i) {
    const int j = threadIdx.x + (i << 8);
    s = fmaf(a[base + j], c[base + j], s);
  }
  s = block_reduce_sum(s, red);
  if (threadIdx.x == 0) out[blockIdx.x] = s;
}

// ---------------- host orchestration ----------------
extern "C" void kernel_launch(void* const* d_in, const int* in_sizes, int n_in,
                              void* d_out, int out_size, void* d_ws, size_t ws_size,
                              hipStream_t stream) {
  (void)in_sizes; (void)n_in; (void)out_size; (void)ws_size;
  const float* ctx   = (const float*)d_in[0];
  const float* asp   = (const float*)d_in[1];
  const float* fc1_w = (const float*)d_in[2];
  const float* fc1_b = (const float*)d_in[3];
  const float* pos   = (const float*)d_in[4];
  const float* emb_g = (const float*)d_in[5];
  const float* emb_b = (const float*)d_in[6];
  const float* Wq    = (const float*)d_in[7];
  const float* bq    = (const float*)d_in[8];
  const float* Wk    = (const float*)d_in[9];
  const float* bk    = (const float*)d_in[10];
  const float* Wv    = (const float*)d_in[11];
  const float* bv    = (const float*)d_in[12];
  const float* Wo    = (const float*)d_in[13];
  const float* bo    = (const float*)d_in[14];
  const float* ln1g  = (const float*)d_in[15];
  const float* ln1b  = (const float*)d_in[16];
  const float* W1    = (const float*)d_in[17];
  const float* bf1   = (const float*)d_in[18];
  const float* W2    = (const float*)d_in[19];
  const float* bf2   = (const float*)d_in[20];
  const float* ln2g  = (const float*)d_in[21];
  const float* ln2b  = (const float*)d_in[22];
  float* out = (float*)d_out;

  // ---- workspace carving (all-f16 activations) ----
  f16* f = (f16*)d_ws;
  size_t o = 0;
  f16* fc1T  = f + o; o += (size_t)DD * KPAD;
  f16* WqkvT = f + o; o += (size_t)NLAYER * 3 * DD * DD;
  f16* WoT   = f + o; o += (size_t)NLAYER * DD * DD;
  f16* W1T   = f + o; o += (size_t)NLAYER * FFD * DD;
  f16* W2T   = f + o; o += (size_t)NLAYER * DD * FFD;
  f16* R     = f + o; o += (size_t)NALL * FFD;     // alias: probes | xpad | qkv+ao | mid
  f16* tmp16 = f + o; o += (size_t)NALL * DD;
  f16* h0f16 = f + o; o += (size_t)NALL * DD;
  f16* hmf16 = f + o; o += (size_t)NALL * DD;
  f16* pp    = f + o; o += (size_t)2 * NALL * DD;  // split-K partials (Wo, FF2)
  f16* outs16[4];
  for (int l = 0; l < 4; ++l) { outs16[l] = f + o; o += (size_t)NALL * DD; }

  f16* xpad = R;
  f16* qkv  = R;
  f16* ao   = R + (size_t)NALL * 3 * DD;
  f16* mid  = R;

  float* g32 = (float*)(f + o);
  size_t o2 = 0;
  float* bqkv = g32 + o2; o2 += (size_t)NLAYER * 3 * DD;
  float* accC = g32 + o2; o2 += (size_t)NB * 4 * DD;
  float* accA = g32 + o2; o2 += (size_t)NB * 4 * DD;
  float* invn = g32 + o2; o2 += NALL;

  // ---- weight prep (z-batched) ----
  transpose_cast_kernel<<<dim3(KPAD / 32, DD / 32, 1), 256, 0, stream>>>(
      fc1_w, fc1T, EMBD, DD, KPAD, 0, 0);
  transpose_cast_kernel<<<dim3(DD / 32, DD / 32, NLAYER), 256, 0, stream>>>(
      Wq, WqkvT, DD, DD, DD, (size_t)DD * DD, (size_t)3 * DD * DD);
  transpose_cast_kernel<<<dim3(DD / 32, DD / 32, NLAYER), 256, 0, stream>>>(
      Wk, WqkvT + (size_t)DD * DD, DD, DD, DD, (size_t)DD * DD, (size_t)3 * DD * DD);
  transpose_cast_kernel<<<dim3(DD / 32, DD / 32, NLAYER), 256, 0, stream>>>(
      Wv, WqkvT + (size_t)2 * DD * DD, DD, DD, DD, (size_t)DD * DD, (size_t)3 * DD * DD);
  transpose_cast_kernel<<<dim3(DD / 32, DD / 32, NLAYER), 256, 0, stream>>>(
      Wo, WoT, DD, DD, DD, (size_t)DD * DD, (size_t)DD * DD);
  transpose_cast_kernel<<<dim3(DD / 32, FFD / 32, NLAYER), 256, 0, stream>>>(
      W1, W1T, DD, FFD, DD, (size_t)DD * FFD, (size_t)FFD * DD);
  transpose_cast_kernel<<<dim3(FFD / 32, DD / 32, NLAYER), 256, 0, stream>>>(
      W2, W2T, FFD, DD, FFD, (size_t)FFD * DD, (size_t)DD * FFD);
  bias_concat_kernel<<<NLAYER, 256, 0, stream>>>(bq, bk, bv, bqkv);

  // ---- ABLATION PROBES (scratch-only; results discarded; run before xpad is live) ----
  gemm_probe<0><<<dim3(NALL / 128, FFD / 128, 2), 256, 0, stream>>>(tmp16, W1T, bf1, R, FFD);
  gemm_probe<1><<<dim3(NALL / 128, FFD / 128, 2), 256, 0, stream>>>(tmp16, W1T, bf1, R, FFD);
  gemm_probe<2><<<dim3(NALL / 128, FFD / 128, 6), 256, 0, stream>>>(tmp16, W1T, bf1, R, FFD);
  gemm_probe<3><<<dim3(NALL / 128, FFD / 128, 8), 256, 0, stream>>>(tmp16, W1T, bf1, R, FFD);

  // ---- merged encoder over 6144 tokens ----
  castpad_kernel<<<NALL, 256, 0, stream>>>(ctx, asp, xpad);
  gemm_3buf<KPAD, 1, 0><<<dim3(NALL / 128, DD / 128), 256, 0, stream>>>(
      xpad, fc1T, fc1_b, tmp16, DD);
  pos_ln16v<<<NALL, 192, 0, stream>>>(tmp16, pos, emb_g, emb_b, h0f16);

  const f16* hin16 = h0f16;
  for (int l = 0; l < NLAYER; ++l) {
    gemm_3buf<DD, 1, 0><<<dim3(NALL / 128, (3 * DD) / 128), 256, 0, stream>>>(
        hin16, WqkvT + (size_t)l * 3 * DD * DD, bqkv + l * 3 * DD, qkv, 3 * DD);
    attn_mfma_kernel<256><<<NB * HEADS, 256, 0, stream>>>(qkv, ao, 0);
    attn_mfma_kernel<128><<<NB * HEADS, 256, 0, stream>>>(qkv, ao, NCTX);
    gemm_3buf<DD, 2, 0><<<dim3(NALL / 128, DD / 128, 2), 256, 0, stream>>>(
        ao, WoT + (size_t)l * DD * DD, bo + l * DD, pp, DD);
    add_ln16v<2><<<NALL, 192, 0, stream>>>(hin16, pp, pp + (size_t)NALL * DD,
                                           ln1g + l * DD, ln1b + l * DD, hmf16);
    gemm_3buf<DD, 1, 1><<<dim3(NALL / 128, FFD / 128), 256, 0, stream>>>(
        hmf16, W1T + (size_t)l * FFD * DD, bf1 + l * FFD, mid, FFD);
    gemm_3buf<FFD, 2, 0><<<dim3(NALL / 128, DD / 128, 2), 256, 0, stream>>>(
        mid, W2T + (size_t)l * DD * FFD, bf2 + l * DD, pp, DD);
    add_ln16v<2><<<NALL, 192, 0, stream>>>(hmf16, pp, pp + (size_t)NALL * DD,
                                           ln2g + l * DD, ln2b + l * DD, outs16[l]);
    hin16 = outs16[l];
  }

  OutsF16 o4;
  for (int i = 0; i < 4; ++i) o4.p[i] = outs16[i];
  invnorm16_kernel<<<NALL, 256, 0, stream>>>(o4, invn);
  normsum16_kernel<<<dim3(NB, 12, 2), 256, 0, stream>>>(o4, invn, accC, accA);
  final_dot_kernel<<<NB, 256, 0, stream>>>(accA, accC, out);
}

// Round 12
// 1055.038 us; speedup vs baseline: 1.4026x; 1.4026x over previous
//
#include <hip/hip_runtime.h>
#include <math.h>

typedef _Float16 f16;
typedef _Float16 h8 __attribute__((ext_vector_type(8)));
typedef _Float16 h4 __attribute__((ext_vector_type(4)));
typedef float f32x4 __attribute__((ext_vector_type(4)));

#define HEADS 12
#define DH 64
#define DD 768
#define FFD 3072
#define EMBD 300
#define KPAD 384
#define NLAYER 4
#define NB 16
#define NCTX 4096           // 16 * 256
#define NALL 6144           // 16*256 + 16*128

// ---------------- block reductions ----------------
__device__ __forceinline__ float block_reduce_sum(float v, float* red) {
  #pragma unroll
  for (int o = 32; o; o >>= 1) v += __shfl_xor(v, o);
  const int wid = threadIdx.x >> 6;
  __syncthreads();
  if ((threadIdx.x & 63) == 0) red[wid] = v;
  __syncthreads();
  float r = red[0];
  #pragma unroll
  for (int w = 1; w < 4; ++w) r += red[w];
  return r;
}

__device__ __forceinline__ float block_reduce_sum3(float v, float* red) {
  #pragma unroll
  for (int o = 32; o; o >>= 1) v += __shfl_xor(v, o);
  const int wid = threadIdx.x >> 6;
  __syncthreads();
  if ((threadIdx.x & 63) == 0) red[wid] = v;
  __syncthreads();
  return red[0] + red[1] + red[2];
}

// ---------------- async global->LDS 16B ----------------
__device__ __forceinline__ void gload16(const f16* g, f16* lds) {
  __builtin_amdgcn_global_load_lds(
      (const __attribute__((address_space(1))) unsigned int*)g,
      (__attribute__((address_space(3))) unsigned int*)lds, 16, 0, 0);
}

// ---------------- weight transpose + cast (z-batched) ----------------
__launch_bounds__(256)
__global__ void transpose_cast_kernel(const float* __restrict__ W, f16* __restrict__ Wt,
                                      int K, int M, int Kpad,
                                      size_t srcStride, size_t dstStride) {
  W += (size_t)blockIdx.z * srcStride;
  Wt += (size_t)blockIdx.z * dstStride;
  __shared__ float t[32][33];
  const int k0 = blockIdx.x * 32, m0 = blockIdx.y * 32;
  const int c = threadIdx.x & 31, r8 = threadIdx.x >> 5;
  #pragma unroll
  for (int p = 0; p < 4; ++p) {
    const int k = k0 + r8 + p * 8;
    t[r8 + p * 8][c] = (k < K && m0 + c < M) ? W[(size_t)k * M + m0 + c] : 0.f;
  }
  __syncthreads();
  #pragma unroll
  for (int p = 0; p < 4; ++p) {
    const int m = m0 + r8 + p * 8;
    const int k = k0 + c;
    if (m < M && k < Kpad) Wt[(size_t)m * Kpad + k] = (f16)t[c][r8 + p * 8];
  }
}

__launch_bounds__(256)
__global__ void castpad_kernel(const float* __restrict__ ctx, const float* __restrict__ asp,
                               f16* __restrict__ xp) {
  const int tok = blockIdx.x;
  const float* src;
  int r;
  if (tok < NCTX) { src = ctx; r = tok; } else { src = asp; r = tok - NCTX; }
  for (int j = threadIdx.x; j < KPAD; j += 256)
    xp[(size_t)tok * KPAD + j] = (j < EMBD) ? (f16)src[(size_t)r * EMBD + j] : (f16)0.f;
}

__launch_bounds__(256)
__global__ void bias_concat_kernel(const float* __restrict__ bq, const float* __restrict__ bk,
                                   const float* __restrict__ bv, float* __restrict__ bqkv) {
  const int l = blockIdx.x;
  for (int j = threadIdx.x; j < DD; j += 256) {
    bqkv[l * 3 * DD + j] = bq[l * DD + j];
    bqkv[l * 3 * DD + DD + j] = bk[l * DD + j];
    bqkv[l * 3 * DD + 2 * DD + j] = bv[l * DD + j];
  }
}

// ---------------- f16 MFMA GEMM: 3-buffer 2-ahead pipeline ----------
#define GBM 128
#define GBN 128
#define GBK 32

template<int K, int KSPLIT, int ACT>
__launch_bounds__(256)
__global__ void gemm_3buf(const f16* __restrict__ A, const f16* __restrict__ Bt,
                          const float* __restrict__ bias, f16* __restrict__ C, int M) {
  constexpr int KB = K / KSPLIT;
  constexpr int NSTEP = KB / GBK;
  __shared__ __align__(16) f16 As[3][GBM * GBK];
  __shared__ __align__(16) f16 Bs[3][GBN * GBK];
  const int tid = threadIdx.x, lane = tid & 63, wid = tid >> 6;
  const int wr = (wid >> 1) * 64, wc = (wid & 1) * 64;
  const int l15 = lane & 15, lg = lane >> 4;

  const int bm = blockIdx.x * GBM;
  const int bn = blockIdx.y * GBN;
  const int kb0 = (KSPLIT > 1) ? blockIdx.z * KB : 0;

  const f16* Ag[2]; const f16* Bg[2];
  int ldsOff[2];
  #pragma unroll
  for (int c = 0; c < 2; ++c) {
    const int v = c * 256 + tid;
    const int row = v >> 2, s = v & 3;
    const int gcol = (s ^ ((row >> 1) & 3)) * 8;
    Ag[c] = A + (size_t)(bm + row) * K + kb0 + gcol;
    Bg[c] = Bt + (size_t)(bn + row) * K + kb0 + gcol;
    ldsOff[c] = (c * 256 + wid * 64) * 8;
  }

  f32x4 acc[4][4] = {};

  #pragma unroll
  for (int c = 0; c < 2; ++c) {
    gload16(Ag[c], &As[0][ldsOff[c]]);
    gload16(Bg[c], &Bs[0][ldsOff[c]]);
  }
  #pragma unroll
  for (int c = 0; c < 2; ++c) {
    gload16(Ag[c] + GBK, &As[1][ldsOff[c]]);
    gload16(Bg[c] + GBK, &Bs[1][ldsOff[c]]);
  }

  int s3 = 0;
  for (int t = 0; t < NSTEP; ++t) {
    if (t + 1 < NSTEP) asm volatile("s_waitcnt vmcnt(4)" ::: "memory");
    else               asm volatile("s_waitcnt vmcnt(0)" ::: "memory");
    __builtin_amdgcn_s_barrier();
    if (t + 2 < NSTEP) {
      const int sn = (s3 + 2 >= 3) ? s3 - 1 : s3 + 2;
      const int kb = (t + 2) * GBK;
      #pragma unroll
      for (int c = 0; c < 2; ++c) {
        gload16(Ag[c] + kb, &As[sn][ldsOff[c]]);
        gload16(Bg[c] + kb, &Bs[sn][ldsOff[c]]);
      }
    }
    h8 af[4], bf[4];
    #pragma unroll
    for (int m = 0; m < 4; ++m) {
      const int row = wr + m * 16 + l15;
      af[m] = *(const h8*)&As[s3][(row * 4 + (lg ^ ((row >> 1) & 3))) * 8];
    }
    #pragma unroll
    for (int n = 0; n < 4; ++n) {
      const int row = wc + n * 16 + l15;
      bf[n] = *(const h8*)&Bs[s3][(row * 4 + (lg ^ ((row >> 1) & 3))) * 8];
    }
    #pragma unroll
    for (int m = 0; m < 4; ++m)
      #pragma unroll
      for (int n = 0; n < 4; ++n)
        acc[m][n] = __builtin_amdgcn_mfma_f32_16x16x32_f16(af[m], bf[n], acc[m][n], 0, 0, 0);
    s3 = (s3 + 1 >= 3) ? 0 : s3 + 1;
  }

  f16* Co = C + ((KSPLIT > 1) ? (size_t)blockIdx.z * NALL * M : (size_t)0);
  #pragma unroll
  for (int m = 0; m < 4; ++m) {
    #pragma unroll
    for (int n = 0; n < 4; ++n) {
      #pragma unroll
      for (int r = 0; r < 4; ++r) {
        const int row = bm + wr + m * 16 + lg * 4 + r;
        const int col = bn + wc + n * 16 + l15;
        float v = acc[m][n][r];
        if (KSPLIT == 1 || blockIdx.z == 0) v += bias[col];
        if (ACT == 1) {
          const float u = 1.5957691216057308f * (v + 0.044715f * v * v * v);
          v = v / (1.f + __expf(-u));
        }
        Co[(size_t)row * M + col] = (f16)v;
      }
    }
  }
}

// ---------------- MFMA attention: block per (b,h,q-half); sums 2 qkv partials ----
template<int S>
__launch_bounds__(256)
__global__ void attn_mfma_kernel(const f16* __restrict__ qkv0, const f16* __restrict__ qkv1,
                                 f16* __restrict__ ao, int tokoff) {
  constexpr int KSTR = 88;
  constexpr int VSTR = 264;
  constexpr int NT = S / 16;
  __shared__ __align__(16) f16 Ks[S][KSTR];
  __shared__ __align__(16) f16 Vt[DH][VSTR];
  __shared__ __align__(16) f16 Pl[4][16][VSTR];
  const int b = blockIdx.x / HEADS, h = blockIdx.x % HEADS;
  const int tid = threadIdx.x, lane = tid & 63, wid = tid >> 6;
  const int l15 = lane & 15, lg = lane >> 4;
  const int qlo = blockIdx.y * (NT / 2);
  const size_t base = (size_t)(tokoff + b * S) * (3 * DD) + (size_t)h * DH;
  const f16* qg0 = qkv0 + base;
  const f16* qg1 = qkv1 + base;
  const f16* kg0 = qkv0 + base + DD;
  const f16* kg1 = qkv1 + base + DD;
  const f16* vg0 = qkv0 + base + 2 * DD;
  const f16* vg1 = qkv1 + base + 2 * DD;

  for (int c = tid; c < S * 8; c += 256) {
    const int row = c >> 3, off = (c & 7) * 8;
    const size_t go = (size_t)row * (3 * DD) + off;
    *(h8*)&Ks[row][off] = *(const h8*)&kg0[go] + *(const h8*)&kg1[go];
    const h8 vv = *(const h8*)&vg0[go] + *(const h8*)&vg1[go];
    #pragma unroll
    for (int j = 0; j < 8; ++j) Vt[off + j][row] = vv[j];
  }
  __syncthreads();

  for (int qt = qlo + wid; qt < qlo + NT / 2; qt += 4) {
    const int q0 = qt * 16;
    h8 aq[2];
    #pragma unroll
    for (int s = 0; s < 2; ++s) {
      const size_t go = (size_t)(q0 + l15) * (3 * DD) + s * 32 + lg * 8;
      aq[s] = *(const h8*)&qg0[go] + *(const h8*)&qg1[go];
    }

    f32x4 sc[NT];
    #pragma unroll
    for (int kt = 0; kt < NT; ++kt) {
      f32x4 c = {};
      const h8 b0 = *(const h8*)&Ks[kt * 16 + l15][lg * 8];
      const h8 b1 = *(const h8*)&Ks[kt * 16 + l15][32 + lg * 8];
      c = __builtin_amdgcn_mfma_f32_16x16x32_f16(aq[0], b0, c, 0, 0, 0);
      c = __builtin_amdgcn_mfma_f32_16x16x32_f16(aq[1], b1, c, 0, 0, 0);
      sc[kt] = c;
    }
    float mx[4], zz[4];
    #pragma unroll
    for (int r = 0; r < 4; ++r) {
      float m = -1e30f;
      #pragma unroll
      for (int kt = 0; kt < NT; ++kt) m = fmaxf(m, sc[kt][r]);
      #pragma unroll
      for (int o = 1; o < 16; o <<= 1) m = fmaxf(m, __shfl_xor(m, o));
      mx[r] = m; zz[r] = 0.f;
    }
    #pragma unroll
    for (int kt = 0; kt < NT; ++kt)
      #pragma unroll
      for (int r = 0; r < 4; ++r) {
        const float p = __expf((sc[kt][r] - mx[r]) * 0.125f);
        zz[r] += p;
        Pl[wid][lg * 4 + r][kt * 16 + l15] = (f16)p;
      }
    #pragma unroll
    for (int r = 0; r < 4; ++r) {
      #pragma unroll
      for (int o = 1; o < 16; o <<= 1) zz[r] += __shfl_xor(zz[r], o);
      zz[r] = 1.f / zz[r];
    }
    // Pl is wave-private; same-wave LDS ordering, no barrier needed.
    f32x4 o4[4] = {};
    #pragma unroll
    for (int ks = 0; ks < S / 32; ++ks) {
      const h8 pa = *(const h8*)&Pl[wid][l15][ks * 32 + lg * 8];
      #pragma unroll
      for (int n = 0; n < 4; ++n) {
        const h8 bv_ = *(const h8*)&Vt[n * 16 + l15][ks * 32 + lg * 8];
        o4[n] = __builtin_amdgcn_mfma_f32_16x16x32_f16(pa, bv_, o4[n], 0, 0, 0);
      }
    }
    #pragma unroll
    for (int n = 0; n < 4; ++n)
      #pragma unroll
      for (int r = 0; r < 4; ++r) {
        const int row = q0 + lg * 4 + r;
        ao[(size_t)(tokoff + b * S + row) * DD + h * DH + n * 16 + l15] = (f16)(o4[n][r] * zz[r]);
      }
  }
}

// ---------------- vectorized LN kernels (192 threads, h4 = 8B/lane) ----------------
__launch_bounds__(192)
__global__ void pos_ln16v(const f16* __restrict__ tmp, const float* __restrict__ pos,
                          const float* __restrict__ g, const float* __restrict__ be,
                          f16* __restrict__ out) {
  __shared__ float red[3];
  const int tok = blockIdx.x;
  const int s = (tok < NCTX) ? (tok & 255) : (tok & 127);
  const size_t row = (size_t)tok * DD;
  const int j = threadIdx.x * 4;
  const h4 a = *(const h4*)&tmp[row + j];
  const float4 p = *(const float4*)&pos[(size_t)s * DD + j];
  float x[4] = { (float)a[0] + p.x, (float)a[1] + p.y, (float)a[2] + p.z, (float)a[3] + p.w };
  float sm = 0.f, ss = 0.f;
  #pragma unroll
  for (int i = 0; i < 4; ++i) { sm += x[i]; ss += x[i] * x[i]; }
  sm = block_reduce_sum3(sm, red);
  ss = block_reduce_sum3(ss, red);
  const float mean = sm * (1.f / DD);
  const float inv = rsqrtf(ss * (1.f / DD) - mean * mean + 1e-12f);
  const float4 gv = *(const float4*)&g[j];
  const float4 bv = *(const float4*)&be[j];
  h4 o;
  o[0] = (f16)((x[0] - mean) * inv * gv.x + bv.x);
  o[1] = (f16)((x[1] - mean) * inv * gv.y + bv.y);
  o[2] = (f16)((x[2] - mean) * inv * gv.z + bv.z);
  o[3] = (f16)((x[3] - mean) * inv * gv.w + bv.w);
  *(h4*)&out[row + j] = o;
}

template<int ND>
__launch_bounds__(192)
__global__ void add_ln16v(const f16* __restrict__ hin, const f16* __restrict__ d0,
                          const f16* __restrict__ d1,
                          const float* __restrict__ g, const float* __restrict__ be,
                          f16* __restrict__ out) {
  __shared__ float red[3];
  const size_t row = (size_t)blockIdx.x * DD;
  const int j = threadIdx.x * 4;
  const h4 a = *(const h4*)&hin[row + j];
  const h4 b = *(const h4*)&d0[row + j];
  h4 c = {};
  if (ND == 2) c = *(const h4*)&d1[row + j];
  float x[4]; float sm = 0.f, ss = 0.f;
  #pragma unroll
  for (int i = 0; i < 4; ++i) {
    float v = (float)a[i] + (float)b[i];
    if (ND == 2) v += (float)c[i];
    x[i] = v; sm += v; ss += v * v;
  }
  sm = block_reduce_sum3(sm, red);
  ss = block_reduce_sum3(ss, red);
  const float mean = sm * (1.f / DD);
  const float inv = rsqrtf(ss * (1.f / DD) - mean * mean + 1e-12f);
  const float4 gv = *(const float4*)&g[j];
  const float4 bv = *(const float4*)&be[j];
  h4 o;
  o[0] = (f16)((x[0] - mean) * inv * gv.x + bv.x);
  o[1] = (f16)((x[1] - mean) * inv * gv.y + bv.y);
  o[2] = (f16)((x[2] - mean) * inv * gv.z + bv.z);
  o[3] = (f16)((x[3] - mean) * inv * gv.w + bv.w);
  *(h4*)&out[row + j] = o;
}

// ---------------- final cosine reduction ----------------
struct OutsF16 { const f16* p[4]; };

__launch_bounds__(256)
__global__ void invnorm16_kernel(OutsF16 o4, float* __restrict__ invn) {
  __shared__ float red[4];
  const size_t row = (size_t)blockIdx.x * DD;
  float ss = 0.f;
  #pragma unroll
  for (int l = 0; l < 4; ++l)
    #pragma unroll
    for (int i = 0; i < 3; ++i) {
      const float v = (float)o4.p[l][row + threadIdx.x + (i << 8)];
      ss += v * v;
    }
  ss = block_reduce_sum(ss, red);
  if (threadIdx.x == 0) invn[blockIdx.x] = 1.f / fmaxf(sqrtf(ss), 1e-8f);
}

__launch_bounds__(256)
__global__ void normsum16_kernel(OutsF16 o4, const float* __restrict__ invn,
                                 float* __restrict__ accC, float* __restrict__ accA) {
  const int b = blockIdx.x;
  const int l = blockIdx.y / 3;
  const int j = (blockIdx.y % 3) * 256 + threadIdx.x;
  const int pass = blockIdx.z;
  const int S = pass ? 128 : 256;
  const int tb = pass ? (NCTX + b * 128) : (b * 256);
  float* acc = pass ? accA : accC;
  const f16* __restrict__ src = o4.p[l];
  float s = 0.f;
  for (int si = 0; si < S; ++si)
    s = fmaf((float)src[(size_t)(tb + si) * DD + j], invn[tb + si], s);
  acc[(size_t)b * (4 * DD) + (size_t)l * DD + j] = s;
}

__launch_bounds__(256)
__global__ void final_dot_kernel(const float* __restrict__ a, const float* __restrict__ c,
                                 float* __restrict__ out) {
  __shared__ float red[4];
  const size_t base = (size_t)blockIdx.x * (4 * DD);
  float s = 0.f;
  #pragma unroll
  for (int i = 0; i < 12; ++i) {
    const int j = threadIdx.x + (i << 8);
    s = fmaf(a[base + j], c[base + j], s);
  }
  s = block_reduce_sum(s, red);
  if (threadIdx.x == 0) out[blockIdx.x] = s;
}

// ---------------- host orchestration ----------------
extern "C" void kernel_launch(void* const* d_in, const int* in_sizes, int n_in,
                              void* d_out, int out_size, void* d_ws, size_t ws_size,
                              hipStream_t stream) {
  (void)in_sizes; (void)n_in; (void)out_size; (void)ws_size;
  const float* ctx   = (const float*)d_in[0];
  const float* asp   = (const float*)d_in[1];
  const float* fc1_w = (const float*)d_in[2];
  const float* fc1_b = (const float*)d_in[3];
  const float* pos   = (const float*)d_in[4];
  const float* emb_g = (const float*)d_in[5];
  const float* emb_b = (const float*)d_in[6];
  const float* Wq    = (const float*)d_in[7];
  const float* bq    = (const float*)d_in[8];
  const float* Wk    = (const float*)d_in[9];
  const float* bk    = (const float*)d_in[10];
  const float* Wv    = (const float*)d_in[11];
  const float* bv    = (const float*)d_in[12];
  const float* Wo    = (const float*)d_in[13];
  const float* bo    = (const float*)d_in[14];
  const float* ln1g  = (const float*)d_in[15];
  const float* ln1b  = (const float*)d_in[16];
  const float* W1    = (const float*)d_in[17];
  const float* bf1   = (const float*)d_in[18];
  const float* W2    = (const float*)d_in[19];
  const float* bf2   = (const float*)d_in[20];
  const float* ln2g  = (const float*)d_in[21];
  const float* ln2b  = (const float*)d_in[22];
  float* out = (float*)d_out;

  // ---- workspace carving (all-f16 activations) ----
  f16* f = (f16*)d_ws;
  size_t o = 0;
  f16* fc1T  = f + o; o += (size_t)DD * KPAD;
  f16* WqkvT = f + o; o += (size_t)NLAYER * 3 * DD * DD;
  f16* WoT   = f + o; o += (size_t)NLAYER * DD * DD;
  f16* W1T   = f + o; o += (size_t)NLAYER * FFD * DD;
  f16* W2T   = f + o; o += (size_t)NLAYER * DD * FFD;
  f16* R     = f + o; o += (size_t)NALL * 7 * DD;  // qkv(2x3DD partials) + ao(DD); mid aliases
  f16* tmp16 = f + o; o += (size_t)NALL * DD;
  f16* h0f16 = f + o; o += (size_t)NALL * DD;
  f16* hmf16 = f + o; o += (size_t)NALL * DD;
  f16* pp    = f + o; o += (size_t)2 * NALL * DD;  // split-K partials (Wo, FF2)
  f16* outs16[4];
  for (int l = 0; l < 4; ++l) { outs16[l] = f + o; o += (size_t)NALL * DD; }

  f16* xpad = R;
  f16* qkv0 = R;                                   // partial z=0 (with bias)
  f16* qkv1 = R + (size_t)NALL * 3 * DD;           // partial z=1
  f16* ao   = R + (size_t)NALL * 6 * DD;
  f16* mid  = R;                                   // FF1 out (qkv dead by then)

  float* g32 = (float*)(f + o);
  size_t o2 = 0;
  float* bqkv = g32 + o2; o2 += (size_t)NLAYER * 3 * DD;
  float* accC = g32 + o2; o2 += (size_t)NB * 4 * DD;
  float* accA = g32 + o2; o2 += (size_t)NB * 4 * DD;
  float* invn = g32 + o2; o2 += NALL;

  // ---- weight prep (z-batched) ----
  transpose_cast_kernel<<<dim3(KPAD / 32, DD / 32, 1), 256, 0, stream>>>(
      fc1_w, fc1T, EMBD, DD, KPAD, 0, 0);
  transpose_cast_kernel<<<dim3(DD / 32, DD / 32, NLAYER), 256, 0, stream>>>(
      Wq, WqkvT, DD, DD, DD, (size_t)DD * DD, (size_t)3 * DD * DD);
  transpose_cast_kernel<<<dim3(DD / 32, DD / 32, NLAYER), 256, 0, stream>>>(
      Wk, WqkvT + (size_t)DD * DD, DD, DD, DD, (size_t)DD * DD, (size_t)3 * DD * DD);
  transpose_cast_kernel<<<dim3(DD / 32, DD / 32, NLAYER), 256, 0, stream>>>(
      Wv, WqkvT + (size_t)2 * DD * DD, DD, DD, DD, (size_t)DD * DD, (size_t)3 * DD * DD);
  transpose_cast_kernel<<<dim3(DD / 32, DD / 32, NLAYER), 256, 0, stream>>>(
      Wo, WoT, DD, DD, DD, (size_t)DD * DD, (size_t)DD * DD);
  transpose_cast_kernel<<<dim3(DD / 32, FFD / 32, NLAYER), 256, 0, stream>>>(
      W1, W1T, DD, FFD, DD, (size_t)DD * FFD, (size_t)FFD * DD);
  transpose_cast_kernel<<<dim3(FFD / 32, DD / 32, NLAYER), 256, 0, stream>>>(
      W2, W2T, FFD, DD, FFD, (size_t)FFD * DD, (size_t)DD * FFD);
  bias_concat_kernel<<<NLAYER, 256, 0, stream>>>(bq, bk, bv, bqkv);

  // ---- merged encoder over 6144 tokens ----
  castpad_kernel<<<NALL, 256, 0, stream>>>(ctx, asp, xpad);
  gemm_3buf<KPAD, 1, 0><<<dim3(NALL / 128, DD / 128), 256, 0, stream>>>(
      xpad, fc1T, fc1_b, tmp16, DD);
  pos_ln16v<<<NALL, 192, 0, stream>>>(tmp16, pos, emb_g, emb_b, h0f16);

  const f16* hin16 = h0f16;
  for (int l = 0; l < NLAYER; ++l) {
    // QKV split-K=2: partials at qkv0/qkv1, summed inside attention staging
    gemm_3buf<DD, 2, 0><<<dim3(NALL / 128, (3 * DD) / 128, 2), 256, 0, stream>>>(
        hin16, WqkvT + (size_t)l * 3 * DD * DD, bqkv + l * 3 * DD, qkv0, 3 * DD);
    attn_mfma_kernel<256><<<dim3(NB * HEADS, 2), 256, 0, stream>>>(qkv0, qkv1, ao, 0);
    attn_mfma_kernel<128><<<dim3(NB * HEADS, 2), 256, 0, stream>>>(qkv0, qkv1, ao, NCTX);
    gemm_3buf<DD, 2, 0><<<dim3(NALL / 128, DD / 128, 2), 256, 0, stream>>>(
        ao, WoT + (size_t)l * DD * DD, bo + l * DD, pp, DD);
    add_ln16v<2><<<NALL, 192, 0, stream>>>(hin16, pp, pp + (size_t)NALL * DD,
                                           ln1g + l * DD, ln1b + l * DD, hmf16);
    gemm_3buf<DD, 1, 1><<<dim3(NALL / 128, FFD / 128), 256, 0, stream>>>(
        hmf16, W1T + (size_t)l * FFD * DD, bf1 + l * FFD, mid, FFD);
    gemm_3buf<FFD, 2, 0><<<dim3(NALL / 128, DD / 128, 2), 256, 0, stream>>>(
        mid, W2T + (size_t)l * DD * FFD, bf2 + l * DD, pp, DD);
    add_ln16v<2><<<NALL, 192, 0, stream>>>(hmf16, pp, pp + (size_t)NALL * DD,
                                           ln2g + l * DD, ln2b + l * DD, outs16[l]);
    hin16 = outs16[l];
  }

  OutsF16 o4;
  for (int i = 0; i < 4; ++i) o4.p[i] = outs16[i];
  invnorm16_kernel<<<NALL, 256, 0, stream>>>(o4, invn);
  normsum16_kernel<<<dim3(NB, 12, 2), 256, 0, stream>>>(o4, invn, accC, accA);
  final_dot_kernel<<<NB, 256, 0, stream>>>(accA, accC, out);
}

// Round 13
// 1037.467 us; speedup vs baseline: 1.4264x; 1.0169x over previous
//
#include <hip/hip_runtime.h>
#include <math.h>

typedef _Float16 f16;
typedef _Float16 h8 __attribute__((ext_vector_type(8)));
typedef _Float16 h4 __attribute__((ext_vector_type(4)));
typedef float f32x4 __attribute__((ext_vector_type(4)));

#define HEADS 12
#define DH 64
#define DD 768
#define FFD 3072
#define EMBD 300
#define KPAD 384
#define NLAYER 4
#define NB 16
#define NCTX 4096           // 16 * 256
#define NALL 6144           // 16*256 + 16*128

// ---------------- block reductions ----------------
__device__ __forceinline__ float block_reduce_sum(float v, float* red) {
  #pragma unroll
  for (int o = 32; o; o >>= 1) v += __shfl_xor(v, o);
  const int wid = threadIdx.x >> 6;
  __syncthreads();
  if ((threadIdx.x & 63) == 0) red[wid] = v;
  __syncthreads();
  float r = red[0];
  #pragma unroll
  for (int w = 1; w < 4; ++w) r += red[w];
  return r;
}

__device__ __forceinline__ float block_reduce_sum3(float v, float* red) {
  #pragma unroll
  for (int o = 32; o; o >>= 1) v += __shfl_xor(v, o);
  const int wid = threadIdx.x >> 6;
  __syncthreads();
  if ((threadIdx.x & 63) == 0) red[wid] = v;
  __syncthreads();
  return red[0] + red[1] + red[2];
}

// ---------------- async global->LDS 16B ----------------
__device__ __forceinline__ void gload16(const f16* g, f16* lds) {
  __builtin_amdgcn_global_load_lds(
      (const __attribute__((address_space(1))) unsigned int*)g,
      (__attribute__((address_space(3))) unsigned int*)lds, 16, 0, 0);
}

// ---------------- weight transpose + cast (z-batched) ----------------
__launch_bounds__(256)
__global__ void transpose_cast_kernel(const float* __restrict__ W, f16* __restrict__ Wt,
                                      int K, int M, int Kpad,
                                      size_t srcStride, size_t dstStride) {
  W += (size_t)blockIdx.z * srcStride;
  Wt += (size_t)blockIdx.z * dstStride;
  __shared__ float t[32][33];
  const int k0 = blockIdx.x * 32, m0 = blockIdx.y * 32;
  const int c = threadIdx.x & 31, r8 = threadIdx.x >> 5;
  #pragma unroll
  for (int p = 0; p < 4; ++p) {
    const int k = k0 + r8 + p * 8;
    t[r8 + p * 8][c] = (k < K && m0 + c < M) ? W[(size_t)k * M + m0 + c] : 0.f;
  }
  __syncthreads();
  #pragma unroll
  for (int p = 0; p < 4; ++p) {
    const int m = m0 + r8 + p * 8;
    const int k = k0 + c;
    if (m < M && k < Kpad) Wt[(size_t)m * Kpad + k] = (f16)t[c][r8 + p * 8];
  }
}

__launch_bounds__(256)
__global__ void castpad_kernel(const float* __restrict__ ctx, const float* __restrict__ asp,
                               f16* __restrict__ xp) {
  const int tok = blockIdx.x;
  const float* src;
  int r;
  if (tok < NCTX) { src = ctx; r = tok; } else { src = asp; r = tok - NCTX; }
  for (int j = threadIdx.x; j < KPAD; j += 256)
    xp[(size_t)tok * KPAD + j] = (j < EMBD) ? (f16)src[(size_t)r * EMBD + j] : (f16)0.f;
}

__launch_bounds__(256)
__global__ void bias_concat_kernel(const float* __restrict__ bq, const float* __restrict__ bk,
                                   const float* __restrict__ bv, float* __restrict__ bqkv) {
  const int l = blockIdx.x;
  for (int j = threadIdx.x; j < DD; j += 256) {
    bqkv[l * 3 * DD + j] = bq[l * DD + j];
    bqkv[l * 3 * DD + DD + j] = bk[l * DD + j];
    bqkv[l * 3 * DD + 2 * DD + j] = bv[l * DD + j];
  }
}

// ---------------- 128^2 f16 MFMA GEMM: 3-buffer 2-ahead (narrow-M / split-K) ----
#define GBM 128
#define GBN 128
#define GBK 32

template<int K, int KSPLIT, int ACT>
__launch_bounds__(256)
__global__ void gemm_3buf(const f16* __restrict__ A, const f16* __restrict__ Bt,
                          const float* __restrict__ bias, f16* __restrict__ C, int M) {
  constexpr int KB = K / KSPLIT;
  constexpr int NSTEP = KB / GBK;
  __shared__ __align__(16) f16 As[3][GBM * GBK];
  __shared__ __align__(16) f16 Bs[3][GBN * GBK];
  const int tid = threadIdx.x, lane = tid & 63, wid = tid >> 6;
  const int wr = (wid >> 1) * 64, wc = (wid & 1) * 64;
  const int l15 = lane & 15, lg = lane >> 4;

  const int bm = blockIdx.x * GBM;
  const int bn = blockIdx.y * GBN;
  const int kb0 = (KSPLIT > 1) ? blockIdx.z * KB : 0;

  const f16* Ag[2]; const f16* Bg[2];
  int ldsOff[2];
  #pragma unroll
  for (int c = 0; c < 2; ++c) {
    const int v = c * 256 + tid;
    const int row = v >> 2, s = v & 3;
    const int gcol = (s ^ ((row >> 1) & 3)) * 8;
    Ag[c] = A + (size_t)(bm + row) * K + kb0 + gcol;
    Bg[c] = Bt + (size_t)(bn + row) * K + kb0 + gcol;
    ldsOff[c] = (c * 256 + wid * 64) * 8;
  }

  f32x4 acc[4][4] = {};

  #pragma unroll
  for (int c = 0; c < 2; ++c) {
    gload16(Ag[c], &As[0][ldsOff[c]]);
    gload16(Bg[c], &Bs[0][ldsOff[c]]);
  }
  #pragma unroll
  for (int c = 0; c < 2; ++c) {
    gload16(Ag[c] + GBK, &As[1][ldsOff[c]]);
    gload16(Bg[c] + GBK, &Bs[1][ldsOff[c]]);
  }

  int s3 = 0;
  for (int t = 0; t < NSTEP; ++t) {
    if (t + 1 < NSTEP) asm volatile("s_waitcnt vmcnt(4)" ::: "memory");
    else               asm volatile("s_waitcnt vmcnt(0)" ::: "memory");
    __builtin_amdgcn_s_barrier();
    if (t + 2 < NSTEP) {
      const int sn = (s3 + 2 >= 3) ? s3 - 1 : s3 + 2;
      const int kb = (t + 2) * GBK;
      #pragma unroll
      for (int c = 0; c < 2; ++c) {
        gload16(Ag[c] + kb, &As[sn][ldsOff[c]]);
        gload16(Bg[c] + kb, &Bs[sn][ldsOff[c]]);
      }
    }
    h8 af[4], bf[4];
    #pragma unroll
    for (int m = 0; m < 4; ++m) {
      const int row = wr + m * 16 + l15;
      af[m] = *(const h8*)&As[s3][(row * 4 + (lg ^ ((row >> 1) & 3))) * 8];
    }
    #pragma unroll
    for (int n = 0; n < 4; ++n) {
      const int row = wc + n * 16 + l15;
      bf[n] = *(const h8*)&Bs[s3][(row * 4 + (lg ^ ((row >> 1) & 3))) * 8];
    }
    #pragma unroll
    for (int m = 0; m < 4; ++m)
      #pragma unroll
      for (int n = 0; n < 4; ++n)
        acc[m][n] = __builtin_amdgcn_mfma_f32_16x16x32_f16(af[m], bf[n], acc[m][n], 0, 0, 0);
    s3 = (s3 + 1 >= 3) ? 0 : s3 + 1;
  }

  f16* Co = C + ((KSPLIT > 1) ? (size_t)blockIdx.z * NALL * M : (size_t)0);
  #pragma unroll
  for (int m = 0; m < 4; ++m) {
    #pragma unroll
    for (int n = 0; n < 4; ++n) {
      #pragma unroll
      for (int r = 0; r < 4; ++r) {
        const int row = bm + wr + m * 16 + lg * 4 + r;
        const int col = bn + wc + n * 16 + l15;
        float v = acc[m][n][r];
        if (KSPLIT == 1 || blockIdx.z == 0) v += bias[col];
        if (ACT == 1) {
          const float u = 1.5957691216057308f * (v + 0.044715f * v * v * v);
          v = v / (1.f + __expf(-u));
        }
        Co[(size_t)row * M + col] = (f16)v;
      }
    }
  }
}

// ============ 256x256 8-phase GEMM (T3+T4+T5): BK=64, 8 waves (2Mx4N) ============
// Per K-tile 4 phases; staging units: u0=B rows 0-127, u1=B rows 128-255,
// u2=A rows 0-63 & 128-191, u3=A rows 64-127 & 192-255 (one unit staged/phase,
// 2 gload16/thread). Wait ladder (FIFO vmcnt): steady [2,4,4,6], tail [2,2,0,0].
// LDS granule swizzle: slot g of row r holds global granule g^(r&7) (pre-swizzled
// source; read applies same XOR) -> ~2-way banks.

#define G8_PHASE(BUF, Q, VMN, ...)                                              \
  {                                                                             \
    asm volatile("s_waitcnt vmcnt(" #VMN ")" ::: "memory");                     \
    __builtin_amdgcn_s_barrier();                                               \
    __builtin_amdgcn_sched_barrier(0);                                          \
    h8 af[2][2], bf[4][2];                                                      \
    _Pragma("unroll")                                                           \
    for (int i = 0; i < 2; ++i) {                                               \
      const int row = wr + (2 * (Q) + i) * 16 + l15;                            \
      _Pragma("unroll")                                                         \
      for (int kk = 0; kk < 2; ++kk)                                            \
        af[i][kk] = *(const h8*)&As[BUF][(row * 8 + ((kk * 4 + lg) ^ (row & 7))) * 8]; \
    }                                                                           \
    _Pragma("unroll")                                                           \
    for (int n = 0; n < 4; ++n) {                                               \
      const int row = wc + n * 16 + l15;                                        \
      _Pragma("unroll")                                                         \
      for (int kk = 0; kk < 2; ++kk)                                            \
        bf[n][kk] = *(const h8*)&Bs[BUF][(row * 8 + ((kk * 4 + lg) ^ (row & 7))) * 8]; \
    }                                                                           \
    __VA_ARGS__;                                                                \
    __builtin_amdgcn_s_setprio(1);                                              \
    _Pragma("unroll")                                                           \
    for (int kk = 0; kk < 2; ++kk)                                              \
      _Pragma("unroll")                                                         \
      for (int i = 0; i < 2; ++i)                                               \
        _Pragma("unroll")                                                       \
        for (int n = 0; n < 4; ++n)                                             \
          acc[2 * (Q) + i][n] = __builtin_amdgcn_mfma_f32_16x16x32_f16(         \
              af[i][kk], bf[n][kk], acc[2 * (Q) + i][n], 0, 0, 0);              \
    __builtin_amdgcn_s_setprio(0);                                              \
  }

#define STG_U0(SB, KT) { gload16(sB0a + (KT) * 64, &Bs[SB][(wid * 64) * 8]);          \
                         gload16(sB0b + (KT) * 64, &Bs[SB][(512 + wid * 64) * 8]); }
#define STG_U1(SB, KT) { gload16(sB1a + (KT) * 64, &Bs[SB][(1024 + wid * 64) * 8]);   \
                         gload16(sB1b + (KT) * 64, &Bs[SB][(1536 + wid * 64) * 8]); }
#define STG_U2(SB, KT) { gload16(sA2a + (KT) * 64, &As[SB][(wid * 64) * 8]);          \
                         gload16(sA2b + (KT) * 64, &As[SB][(1024 + wid * 64) * 8]); }
#define STG_U3(SB, KT) { gload16(sA3a + (KT) * 64, &As[SB][(512 + wid * 64) * 8]);    \
                         gload16(sA3b + (KT) * 64, &As[SB][(1536 + wid * 64) * 8]); }

template<int K, int ACT>
__launch_bounds__(512, 1)
__global__ void gemm_8ph(const f16* __restrict__ A, const f16* __restrict__ Bt,
                         const float* __restrict__ bias, f16* __restrict__ C, int M) {
  constexpr int NT = K / 64;          // K-tiles
  constexpr int NITER = NT / 2;
  static_assert(NT % 2 == 0 && NT >= 4, "need even K-tiles >= 4");
  __shared__ __align__(16) f16 As[2][256 * 64];
  __shared__ __align__(16) f16 Bs[2][256 * 64];
  const int tid = threadIdx.x, lane = tid & 63, wid = tid >> 6;
  const int wr = (wid >> 2) * 128, wc = (wid & 3) * 64;
  const int l15 = lane & 15, lg = lane >> 4;
  const int bm = blockIdx.x * 256, bn = blockIdx.y * 256;

  // per-thread pre-swizzled global source pointers (granule base -> row, g=tid&7)
  const int g = tid & 7;
  int r0a = (tid) >> 3;            // u0 c0: B rows 0-63
  int r0b = (512 + tid) >> 3;      // u0 c1: B rows 64-127
  int r1a = (1024 + tid) >> 3;     // u1 c0: B rows 128-191
  int r1b = (1536 + tid) >> 3;     // u1 c1: B rows 192-255
  const f16* sB0a = Bt + (size_t)(bn + r0a) * K + ((g ^ (r0a & 7)) * 8);
  const f16* sB0b = Bt + (size_t)(bn + r0b) * K + ((g ^ (r0b & 7)) * 8);
  const f16* sB1a = Bt + (size_t)(bn + r1a) * K + ((g ^ (r1a & 7)) * 8);
  const f16* sB1b = Bt + (size_t)(bn + r1b) * K + ((g ^ (r1b & 7)) * 8);
  const f16* sA2a = A + (size_t)(bm + r0a) * K + ((g ^ (r0a & 7)) * 8);   // A rows 0-63
  const f16* sA2b = A + (size_t)(bm + r1a) * K + ((g ^ (r1a & 7)) * 8);   // A rows 128-191
  const f16* sA3a = A + (size_t)(bm + r0b) * K + ((g ^ (r0b & 7)) * 8);   // A rows 64-127
  const f16* sA3b = A + (size_t)(bm + r1b) * K + ((g ^ (r1b & 7)) * 8);   // A rows 192-255

  f32x4 acc[8][4] = {};

  // prologue: stage tile 0 (units u0..u3) into buffer 0
  STG_U0(0, 0); STG_U1(0, 0); STG_U2(0, 0); STG_U3(0, 0);

  for (int t = 0; t < NITER - 1; ++t) {
    const int TB = 2 * t + 1, TC = 2 * t + 2;
    // half A: consume tile 2t (buf0), stage tile 2t+1 -> buf1
    G8_PHASE(0, 0, 2, STG_U0(1, TB))
    G8_PHASE(0, 1, 4, STG_U1(1, TB))
    G8_PHASE(0, 2, 4, STG_U2(1, TB))
    G8_PHASE(0, 3, 6, STG_U3(1, TB))
    // half B: consume tile 2t+1 (buf1), stage tile 2t+2 -> buf0
    G8_PHASE(1, 0, 2, STG_U0(0, TC))
    G8_PHASE(1, 1, 4, STG_U1(0, TC))
    G8_PHASE(1, 2, 4, STG_U2(0, TC))
    G8_PHASE(1, 3, 6, STG_U3(0, TC))
  }
  {
    const int TB = NT - 1;
    // final half A: consume tile NT-2 (buf0), stage tile NT-1 -> buf1
    G8_PHASE(0, 0, 2, STG_U0(1, TB))
    G8_PHASE(0, 1, 4, STG_U1(1, TB))
    G8_PHASE(0, 2, 4, STG_U2(1, TB))
    G8_PHASE(0, 3, 6, STG_U3(1, TB))
    // final half B: consume tile NT-1 (buf1), no staging; drain ladder
    G8_PHASE(1, 0, 2, )
    G8_PHASE(1, 1, 2, )
    G8_PHASE(1, 2, 0, )
    G8_PHASE(1, 3, 0, )
  }

  #pragma unroll
  for (int m = 0; m < 8; ++m) {
    #pragma unroll
    for (int n = 0; n < 4; ++n) {
      #pragma unroll
      for (int r = 0; r < 4; ++r) {
        const int row = bm + wr + m * 16 + lg * 4 + r;
        const int col = bn + wc + n * 16 + l15;
        float v = acc[m][n][r] + bias[col];
        if (ACT == 1) {
          const float u = 1.5957691216057308f * (v + 0.044715f * v * v * v);
          v = v / (1.f + __expf(-u));
        }
        C[(size_t)row * M + col] = (f16)v;
      }
    }
  }
}

// ---------------- MFMA attention: one block per (b,h) ----------------
template<int S>
__launch_bounds__(256)
__global__ void attn_mfma_kernel(const f16* __restrict__ qkv, f16* __restrict__ ao, int tokoff) {
  constexpr int KSTR = 88;
  constexpr int VSTR = 264;
  __shared__ __align__(16) f16 Ks[S][KSTR];
  __shared__ __align__(16) f16 Vt[DH][VSTR];
  __shared__ __align__(16) f16 Pl[4][16][VSTR];
  const int b = blockIdx.x / HEADS, h = blockIdx.x % HEADS;
  const int tid = threadIdx.x, lane = tid & 63, wid = tid >> 6;
  const int l15 = lane & 15, lg = lane >> 4;
  const size_t base = (size_t)(tokoff + b * S) * (3 * DD) + (size_t)h * DH;
  const f16* qg = qkv + base;
  const f16* kg = qkv + base + DD;
  const f16* vg = qkv + base + 2 * DD;

  for (int c = tid; c < S * 8; c += 256) {
    const int row = c >> 3, off = (c & 7) * 8;
    *(h8*)&Ks[row][off] = *(const h8*)&kg[(size_t)row * (3 * DD) + off];
    const h8 vv = *(const h8*)&vg[(size_t)row * (3 * DD) + off];
    #pragma unroll
    for (int j = 0; j < 8; ++j) Vt[off + j][row] = vv[j];
  }
  __syncthreads();

  for (int qt = wid; qt < S / 16; qt += 4) {
    const int q0 = qt * 16;
    h8 aq[2];
    #pragma unroll
    for (int s = 0; s < 2; ++s)
      aq[s] = *(const h8*)&qg[(size_t)(q0 + l15) * (3 * DD) + s * 32 + lg * 8];

    f32x4 sc[S / 16];
    #pragma unroll
    for (int kt = 0; kt < S / 16; ++kt) {
      f32x4 c = {};
      const h8 b0 = *(const h8*)&Ks[kt * 16 + l15][lg * 8];
      const h8 b1 = *(const h8*)&Ks[kt * 16 + l15][32 + lg * 8];
      c = __builtin_amdgcn_mfma_f32_16x16x32_f16(aq[0], b0, c, 0, 0, 0);
      c = __builtin_amdgcn_mfma_f32_16x16x32_f16(aq[1], b1, c, 0, 0, 0);
      sc[kt] = c;
    }
    float mx[4], zz[4];
    #pragma unroll
    for (int r = 0; r < 4; ++r) {
      float m = -1e30f;
      #pragma unroll
      for (int kt = 0; kt < S / 16; ++kt) m = fmaxf(m, sc[kt][r]);
      #pragma unroll
      for (int o = 1; o < 16; o <<= 1) m = fmaxf(m, __shfl_xor(m, o));
      mx[r] = m; zz[r] = 0.f;
    }
    #pragma unroll
    for (int kt = 0; kt < S / 16; ++kt)
      #pragma unroll
      for (int r = 0; r < 4; ++r) {
        const float p = __expf((sc[kt][r] - mx[r]) * 0.125f);
        zz[r] += p;
        Pl[wid][lg * 4 + r][kt * 16 + l15] = (f16)p;
      }
    #pragma unroll
    for (int r = 0; r < 4; ++r) {
      #pragma unroll
      for (int o = 1; o < 16; o <<= 1) zz[r] += __shfl_xor(zz[r], o);
      zz[r] = 1.f / zz[r];
    }
    // Pl is wave-private; same-wave LDS ordering, no barrier needed.
    f32x4 o4[4] = {};
    #pragma unroll
    for (int ks = 0; ks < S / 32; ++ks) {
      const h8 pa = *(const h8*)&Pl[wid][l15][ks * 32 + lg * 8];
      #pragma unroll
      for (int n = 0; n < 4; ++n) {
        const h8 bv_ = *(const h8*)&Vt[n * 16 + l15][ks * 32 + lg * 8];
        o4[n] = __builtin_amdgcn_mfma_f32_16x16x32_f16(pa, bv_, o4[n], 0, 0, 0);
      }
    }
    #pragma unroll
    for (int n = 0; n < 4; ++n)
      #pragma unroll
      for (int r = 0; r < 4; ++r) {
        const int row = q0 + lg * 4 + r;
        ao[(size_t)(tokoff + b * S + row) * DD + h * DH + n * 16 + l15] = (f16)(o4[n][r] * zz[r]);
      }
  }
}

// ---------------- vectorized LN kernels (192 threads, h4 = 8B/lane) ----------------
__launch_bounds__(192)
__global__ void pos_ln16v(const f16* __restrict__ tmp, const float* __restrict__ pos,
                          const float* __restrict__ g, const float* __restrict__ be,
                          f16* __restrict__ out) {
  __shared__ float red[3];
  const int tok = blockIdx.x;
  const int s = (tok < NCTX) ? (tok & 255) : (tok & 127);
  const size_t row = (size_t)tok * DD;
  const int j = threadIdx.x * 4;
  const h4 a = *(const h4*)&tmp[row + j];
  const float4 p = *(const float4*)&pos[(size_t)s * DD + j];
  float x[4] = { (float)a[0] + p.x, (float)a[1] + p.y, (float)a[2] + p.z, (float)a[3] + p.w };
  float sm = 0.f, ss = 0.f;
  #pragma unroll
  for (int i = 0; i < 4; ++i) { sm += x[i]; ss += x[i] * x[i]; }
  sm = block_reduce_sum3(sm, red);
  ss = block_reduce_sum3(ss, red);
  const float mean = sm * (1.f / DD);
  const float inv = rsqrtf(ss * (1.f / DD) - mean * mean + 1e-12f);
  const float4 gv = *(const float4*)&g[j];
  const float4 bv = *(const float4*)&be[j];
  h4 o;
  o[0] = (f16)((x[0] - mean) * inv * gv.x + bv.x);
  o[1] = (f16)((x[1] - mean) * inv * gv.y + bv.y);
  o[2] = (f16)((x[2] - mean) * inv * gv.z + bv.z);
  o[3] = (f16)((x[3] - mean) * inv * gv.w + bv.w);
  *(h4*)&out[row + j] = o;
}

template<int ND>
__launch_bounds__(192)
__global__ void add_ln16v(const f16* __restrict__ hin, const f16* __restrict__ d0,
                          const f16* __restrict__ d1,
                          const float* __restrict__ g, const float* __restrict__ be,
                          f16* __restrict__ out) {
  __shared__ float red[3];
  const size_t row = (size_t)blockIdx.x * DD;
  const int j = threadIdx.x * 4;
  const h4 a = *(const h4*)&hin[row + j];
  const h4 b = *(const h4*)&d0[row + j];
  h4 c = {};
  if (ND == 2) c = *(const h4*)&d1[row + j];
  float x[4]; float sm = 0.f, ss = 0.f;
  #pragma unroll
  for (int i = 0; i < 4; ++i) {
    float v = (float)a[i] + (float)b[i];
    if (ND == 2) v += (float)c[i];
    x[i] = v; sm += v; ss += v * v;
  }
  sm = block_reduce_sum3(sm, red);
  ss = block_reduce_sum3(ss, red);
  const float mean = sm * (1.f / DD);
  const float inv = rsqrtf(ss * (1.f / DD) - mean * mean + 1e-12f);
  const float4 gv = *(const float4*)&g[j];
  const float4 bv = *(const float4*)&be[j];
  h4 o;
  o[0] = (f16)((x[0] - mean) * inv * gv.x + bv.x);
  o[1] = (f16)((x[1] - mean) * inv * gv.y + bv.y);
  o[2] = (f16)((x[2] - mean) * inv * gv.z + bv.z);
  o[3] = (f16)((x[3] - mean) * inv * gv.w + bv.w);
  *(h4*)&out[row + j] = o;
}

// ---------------- final cosine reduction ----------------
struct OutsF16 { const f16* p[4]; };

__launch_bounds__(256)
__global__ void invnorm16_kernel(OutsF16 o4, float* __restrict__ invn) {
  __shared__ float red[4];
  const size_t row = (size_t)blockIdx.x * DD;
  float ss = 0.f;
  #pragma unroll
  for (int l = 0; l < 4; ++l)
    #pragma unroll
    for (int i = 0; i < 3; ++i) {
      const float v = (float)o4.p[l][row + threadIdx.x + (i << 8)];
      ss += v * v;
    }
  ss = block_reduce_sum(ss, red);
  if (threadIdx.x == 0) invn[blockIdx.x] = 1.f / fmaxf(sqrtf(ss), 1e-8f);
}

__launch_bounds__(256)
__global__ void normsum16_kernel(OutsF16 o4, const float* __restrict__ invn,
                                 float* __restrict__ accC, float* __restrict__ accA) {
  const int b = blockIdx.x;
  const int l = blockIdx.y / 3;
  const int j = (blockIdx.y % 3) * 256 + threadIdx.x;
  const int pass = blockIdx.z;
  const int S = pass ? 128 : 256;
  const int tb = pass ? (NCTX + b * 128) : (b * 256);
  float* acc = pass ? accA : accC;
  const f16* __restrict__ src = o4.p[l];
  float s = 0.f;
  for (int si = 0; si < S; ++si)
    s = fmaf((float)src[(size_t)(tb + si) * DD + j], invn[tb + si], s);
  acc[(size_t)b * (4 * DD) + (size_t)l * DD + j] = s;
}

__launch_bounds__(256)
__global__ void final_dot_kernel(const float* __restrict__ a, const float* __restrict__ c,
                                 float* __restrict__ out) {
  __shared__ float red[4];
  const size_t base = (size_t)blockIdx.x * (4 * DD);
  float s = 0.f;
  #pragma unroll
  for (int i = 0; i < 12; ++i) {
    const int j = threadIdx.x + (i << 8);
    s = fmaf(a[base + j], c[base + j], s);
  }
  s = block_reduce_sum(s, red);
  if (threadIdx.x == 0) out[blockIdx.x] = s;
}

// ---------------- host orchestration ----------------
extern "C" void kernel_launch(void* const* d_in, const int* in_sizes, int n_in,
                              void* d_out, int out_size, void* d_ws, size_t ws_size,
                              hipStream_t stream) {
  (void)in_sizes; (void)n_in; (void)out_size; (void)ws_size;
  const float* ctx   = (const float*)d_in[0];
  const float* asp   = (const float*)d_in[1];
  const float* fc1_w = (const float*)d_in[2];
  const float* fc1_b = (const float*)d_in[3];
  const float* pos   = (const float*)d_in[4];
  const float* emb_g = (const float*)d_in[5];
  const float* emb_b = (const float*)d_in[6];
  const float* Wq    = (const float*)d_in[7];
  const float* bq    = (const float*)d_in[8];
  const float* Wk    = (const float*)d_in[9];
  const float* bk    = (const float*)d_in[10];
  const float* Wv    = (const float*)d_in[11];
  const float* bv    = (const float*)d_in[12];
  const float* Wo    = (const float*)d_in[13];
  const float* bo    = (const float*)d_in[14];
  const float* ln1g  = (const float*)d_in[15];
  const float* ln1b  = (const float*)d_in[16];
  const float* W1    = (const float*)d_in[17];
  const float* bf1   = (const float*)d_in[18];
  const float* W2    = (const float*)d_in[19];
  const float* bf2   = (const float*)d_in[20];
  const float* ln2g  = (const float*)d_in[21];
  const float* ln2b  = (const float*)d_in[22];
  float* out = (float*)d_out;

  // ---- workspace carving (all-f16 activations) ----
  f16* f = (f16*)d_ws;
  size_t o = 0;
  f16* fc1T  = f + o; o += (size_t)DD * KPAD;
  f16* WqkvT = f + o; o += (size_t)NLAYER * 3 * DD * DD;
  f16* WoT   = f + o; o += (size_t)NLAYER * DD * DD;
  f16* W1T   = f + o; o += (size_t)NLAYER * FFD * DD;
  f16* W2T   = f + o; o += (size_t)NLAYER * DD * FFD;
  f16* R     = f + o; o += (size_t)NALL * FFD;     // alias: xpad | qkv+ao | mid
  f16* tmp16 = f + o; o += (size_t)NALL * DD;
  f16* h0f16 = f + o; o += (size_t)NALL * DD;
  f16* hmf16 = f + o; o += (size_t)NALL * DD;
  f16* pp    = f + o; o += (size_t)2 * NALL * DD;  // split-K partials (Wo, FF2)
  f16* outs16[4];
  for (int l = 0; l < 4; ++l) { outs16[l] = f + o; o += (size_t)NALL * DD; }

  f16* xpad = R;
  f16* qkv  = R;
  f16* ao   = R + (size_t)NALL * 3 * DD;
  f16* mid  = R;

  float* g32 = (float*)(f + o);
  size_t o2 = 0;
  float* bqkv = g32 + o2; o2 += (size_t)NLAYER * 3 * DD;
  float* accC = g32 + o2; o2 += (size_t)NB * 4 * DD;
  float* accA = g32 + o2; o2 += (size_t)NB * 4 * DD;
  float* invn = g32 + o2; o2 += NALL;

  // ---- weight prep (z-batched) ----
  transpose_cast_kernel<<<dim3(KPAD / 32, DD / 32, 1), 256, 0, stream>>>(
      fc1_w, fc1T, EMBD, DD, KPAD, 0, 0);
  transpose_cast_kernel<<<dim3(DD / 32, DD / 32, NLAYER), 256, 0, stream>>>(
      Wq, WqkvT, DD, DD, DD, (size_t)DD * DD, (size_t)3 * DD * DD);
  transpose_cast_kernel<<<dim3(DD / 32, DD / 32, NLAYER), 256, 0, stream>>>(
      Wk, WqkvT + (size_t)DD * DD, DD, DD, DD, (size_t)DD * DD, (size_t)3 * DD * DD);
  transpose_cast_kernel<<<dim3(DD / 32, DD / 32, NLAYER), 256, 0, stream>>>(
      Wv, WqkvT + (size_t)2 * DD * DD, DD, DD, DD, (size_t)DD * DD, (size_t)3 * DD * DD);
  transpose_cast_kernel<<<dim3(DD / 32, DD / 32, NLAYER), 256, 0, stream>>>(
      Wo, WoT, DD, DD, DD, (size_t)DD * DD, (size_t)DD * DD);
  transpose_cast_kernel<<<dim3(DD / 32, FFD / 32, NLAYER), 256, 0, stream>>>(
      W1, W1T, DD, FFD, DD, (size_t)DD * FFD, (size_t)FFD * DD);
  transpose_cast_kernel<<<dim3(FFD / 32, DD / 32, NLAYER), 256, 0, stream>>>(
      W2, W2T, FFD, DD, FFD, (size_t)FFD * DD, (size_t)DD * FFD);
  bias_concat_kernel<<<NLAYER, 256, 0, stream>>>(bq, bk, bv, bqkv);

  // ---- merged encoder over 6144 tokens ----
  castpad_kernel<<<NALL, 256, 0, stream>>>(ctx, asp, xpad);
  gemm_3buf<KPAD, 1, 0><<<dim3(NALL / 128, DD / 128), 256, 0, stream>>>(
      xpad, fc1T, fc1_b, tmp16, DD);
  pos_ln16v<<<NALL, 192, 0, stream>>>(tmp16, pos, emb_g, emb_b, h0f16);

  const f16* hin16 = h0f16;
  for (int l = 0; l < NLAYER; ++l) {
    gemm_8ph<DD, 0><<<dim3(NALL / 256, (3 * DD) / 256), 512, 0, stream>>>(
        hin16, WqkvT + (size_t)l * 3 * DD * DD, bqkv + l * 3 * DD, qkv, 3 * DD);
    attn_mfma_kernel<256><<<NB * HEADS, 256, 0, stream>>>(qkv, ao, 0);
    attn_mfma_kernel<128><<<NB * HEADS, 256, 0, stream>>>(qkv, ao, NCTX);
    gemm_3buf<DD, 2, 0><<<dim3(NALL / 128, DD / 128, 2), 256, 0, stream>>>(
        ao, WoT + (size_t)l * DD * DD, bo + l * DD, pp, DD);
    add_ln16v<2><<<NALL, 192, 0, stream>>>(hin16, pp, pp + (size_t)NALL * DD,
                                           ln1g + l * DD, ln1b + l * DD, hmf16);
    gemm_8ph<DD, 1><<<dim3(NALL / 256, FFD / 256), 512, 0, stream>>>(
        hmf16, W1T + (size_t)l * FFD * DD, bf1 + l * FFD, mid, FFD);
    gemm_3buf<FFD, 2, 0><<<dim3(NALL / 128, DD / 128, 2), 256, 0, stream>>>(
        mid, W2T + (size_t)l * DD * FFD, bf2 + l * DD, pp, DD);
    add_ln16v<2><<<NALL, 192, 0, stream>>>(hmf16, pp, pp + (size_t)NALL * DD,
                                           ln2g + l * DD, ln2b + l * DD, outs16[l]);
    hin16 = outs16[l];
  }

  OutsF16 o4;
  for (int i = 0; i < 4; ++i) o4.p[i] = outs16[i];
  invnorm16_kernel<<<NALL, 256, 0, stream>>>(o4, invn);
  normsum16_kernel<<<dim3(NB, 12, 2), 256, 0, stream>>>(o4, invn, accC, accA);
  final_dot_kernel<<<NB, 256, 0, stream>>>(accA, accC, out);
}

// Round 15
// 905.882 us; speedup vs baseline: 1.6336x; 1.1453x over previous
//
#include <hip/hip_runtime.h>
#include <math.h>

typedef _Float16 f16;
typedef _Float16 h8 __attribute__((ext_vector_type(8)));
typedef _Float16 h4 __attribute__((ext_vector_type(4)));
typedef float f32x4 __attribute__((ext_vector_type(4)));

#define HEADS 12
#define DH 64
#define DD 768
#define FFD 3072
#define EMBD 300
#define KPAD 384
#define NLAYER 4
#define NB 16
#define NCTX 4096           // 16 * 256
#define NALL 6144           // 16*256 + 16*128

// ---------------- block reductions ----------------
__device__ __forceinline__ float block_reduce_sum(float v, float* red) {
  #pragma unroll
  for (int o = 32; o; o >>= 1) v += __shfl_xor(v, o);
  const int wid = threadIdx.x >> 6;
  __syncthreads();
  if ((threadIdx.x & 63) == 0) red[wid] = v;
  __syncthreads();
  float r = red[0];
  #pragma unroll
  for (int w = 1; w < 4; ++w) r += red[w];
  return r;
}

__device__ __forceinline__ float block_reduce_sum3(float v, float* red) {
  #pragma unroll
  for (int o = 32; o; o >>= 1) v += __shfl_xor(v, o);
  const int wid = threadIdx.x >> 6;
  __syncthreads();
  if ((threadIdx.x & 63) == 0) red[wid] = v;
  __syncthreads();
  return red[0] + red[1] + red[2];
}

// ---------------- async global->LDS 16B ----------------
__device__ __forceinline__ void gload16(const f16* g, f16* lds) {
  __builtin_amdgcn_global_load_lds(
      (const __attribute__((address_space(1))) unsigned int*)g,
      (__attribute__((address_space(3))) unsigned int*)lds, 16, 0, 0);
}

// ---------------- weight transpose + cast (z-batched) ----------------
__launch_bounds__(256)
__global__ void transpose_cast_kernel(const float* __restrict__ W, f16* __restrict__ Wt,
                                      int K, int M, int Kpad,
                                      size_t srcStride, size_t dstStride) {
  W += (size_t)blockIdx.z * srcStride;
  Wt += (size_t)blockIdx.z * dstStride;
  __shared__ float t[32][33];
  const int k0 = blockIdx.x * 32, m0 = blockIdx.y * 32;
  const int c = threadIdx.x & 31, r8 = threadIdx.x >> 5;
  #pragma unroll
  for (int p = 0; p < 4; ++p) {
    const int k = k0 + r8 + p * 8;
    t[r8 + p * 8][c] = (k < K && m0 + c < M) ? W[(size_t)k * M + m0 + c] : 0.f;
  }
  __syncthreads();
  #pragma unroll
  for (int p = 0; p < 4; ++p) {
    const int m = m0 + r8 + p * 8;
    const int k = k0 + c;
    if (m < M && k < Kpad) Wt[(size_t)m * Kpad + k] = (f16)t[c][r8 + p * 8];
  }
}

__launch_bounds__(256)
__global__ void castpad_kernel(const float* __restrict__ ctx, const float* __restrict__ asp,
                               f16* __restrict__ xp) {
  const int tok = blockIdx.x;
  const float* src;
  int r;
  if (tok < NCTX) { src = ctx; r = tok; } else { src = asp; r = tok - NCTX; }
  for (int j = threadIdx.x; j < KPAD; j += 256)
    xp[(size_t)tok * KPAD + j] = (j < EMBD) ? (f16)src[(size_t)r * EMBD + j] : (f16)0.f;
}

__launch_bounds__(256)
__global__ void bias_concat_kernel(const float* __restrict__ bq, const float* __restrict__ bk,
                                   const float* __restrict__ bv, float* __restrict__ bqkv) {
  const int l = blockIdx.x;
  for (int j = threadIdx.x; j < DD; j += 256) {
    bqkv[l * 3 * DD + j] = bq[l * DD + j];
    bqkv[l * 3 * DD + DD + j] = bk[l * DD + j];
    bqkv[l * 3 * DD + 2 * DD + j] = bv[l * DD + j];
  }
}

// ======== 128x128 f16 GEMM, 512 threads / 8 waves (2Mx4N), 3-buffer 2-ahead ========
// Wave tile 64x32 (acc 4x2). Per step each thread stages TWO 16B chunks of its
// tensor (waves 0-3 -> A, waves 4-7 -> B): c0 = tid&255 (rows 0-63),
// c1 = c0+256 (rows 64-127) -> full 512-chunk tile coverage. vmcnt(2) keeps
// tile t+1's two loads in flight. 48 KB LDS -> 3 blocks/CU (TLP-first design).
#define GBK 32

template<int K, int KSPLIT, int ACT>
__launch_bounds__(512, 6)
__global__ void gemm_w512(const f16* __restrict__ A, const f16* __restrict__ Bt,
                          const float* __restrict__ bias, f16* __restrict__ C, int M) {
  constexpr int KB = K / KSPLIT;
  constexpr int NSTEP = KB / GBK;
  static_assert(NSTEP >= 3, "need >=3 K-steps");
  __shared__ __align__(16) f16 As[3][128 * GBK];
  __shared__ __align__(16) f16 Bs[3][128 * GBK];
  const int tid = threadIdx.x, lane = tid & 63, wid = tid >> 6;
  const int wr = (wid >> 2) * 64, wc = (wid & 3) * 32;
  const int l15 = lane & 15, lg = lane >> 4;

  const int bm = blockIdx.x * 128;
  const int bn = blockIdx.y * 128;
  const int kb0 = (KSPLIT > 1) ? blockIdx.z * KB : 0;

  // staging: thread stages chunks v0 = tid&255 and v1 = v0+256 of its tensor
  const int v0 = tid & 255, v1 = v0 + 256;
  const int r0 = v0 >> 2, s0 = v0 & 3;
  const int r1 = v1 >> 2, s1 = v1 & 3;
  const int gc0 = (s0 ^ ((r0 >> 1) & 3)) * 8;          // pre-swizzled source cols
  const int gc1 = (s1 ^ ((r1 >> 1) & 3)) * 8;
  const bool isA = (wid < 4);
  const f16* gsrc0 = isA ? A + (size_t)(bm + r0) * K + kb0 + gc0
                         : Bt + (size_t)(bn + r0) * K + kb0 + gc0;
  const f16* gsrc1 = isA ? A + (size_t)(bm + r1) * K + kb0 + gc1
                         : Bt + (size_t)(bn + r1) * K + kb0 + gc1;
  f16* dst0[3]; f16* dst1[3];
  #pragma unroll
  for (int b = 0; b < 3; ++b) {
    dst0[b] = isA ? &As[b][((wid & 3) * 64) * 8]         : &Bs[b][((wid & 3) * 64) * 8];
    dst1[b] = isA ? &As[b][(256 + (wid & 3) * 64) * 8]   : &Bs[b][(256 + (wid & 3) * 64) * 8];
  }

  f32x4 acc[4][2] = {};

  // prologue: stage tiles 0,1
  gload16(gsrc0, dst0[0]);
  gload16(gsrc1, dst1[0]);
  gload16(gsrc0 + GBK, dst0[1]);
  gload16(gsrc1 + GBK, dst1[1]);

  int b3 = 0;
  for (int t = 0; t < NSTEP; ++t) {
    if (t + 1 < NSTEP) asm volatile("s_waitcnt vmcnt(2)" ::: "memory");
    else               asm volatile("s_waitcnt vmcnt(0)" ::: "memory");
    __builtin_amdgcn_s_barrier();
    if (t + 2 < NSTEP) {
      const int sn = (b3 + 2 >= 3) ? b3 - 1 : b3 + 2;
      gload16(gsrc0 + (t + 2) * GBK, dst0[sn]);
      gload16(gsrc1 + (t + 2) * GBK, dst1[sn]);
    }
    h8 af[4], bf[2];
    #pragma unroll
    for (int m = 0; m < 4; ++m) {
      const int row = wr + m * 16 + l15;
      af[m] = *(const h8*)&As[b3][(row * 4 + (lg ^ ((row >> 1) & 3))) * 8];
    }
    #pragma unroll
    for (int n = 0; n < 2; ++n) {
      const int row = wc + n * 16 + l15;
      bf[n] = *(const h8*)&Bs[b3][(row * 4 + (lg ^ ((row >> 1) & 3))) * 8];
    }
    #pragma unroll
    for (int m = 0; m < 4; ++m)
      #pragma unroll
      for (int n = 0; n < 2; ++n)
        acc[m][n] = __builtin_amdgcn_mfma_f32_16x16x32_f16(af[m], bf[n], acc[m][n], 0, 0, 0);
    b3 = (b3 + 1 >= 3) ? 0 : b3 + 1;
  }

  f16* Co = C + ((KSPLIT > 1) ? (size_t)blockIdx.z * NALL * M : (size_t)0);
  #pragma unroll
  for (int m = 0; m < 4; ++m) {
    #pragma unroll
    for (int n = 0; n < 2; ++n) {
      #pragma unroll
      for (int r = 0; r < 4; ++r) {
        const int row = bm + wr + m * 16 + lg * 4 + r;
        const int col = bn + wc + n * 16 + l15;
        float vv = acc[m][n][r];
        if (KSPLIT == 1 || blockIdx.z == 0) vv += bias[col];
        if (ACT == 1) {
          const float u = 1.5957691216057308f * (vv + 0.044715f * vv * vv * vv);
          vv = vv / (1.f + __expf(-u));
        }
        Co[(size_t)row * M + col] = (f16)vv;
      }
    }
  }
}

// ---------------- MFMA attention: merged ctx+asp, one dispatch ----------------
#define KSTR 88
#define VSTR 264

template<int S>
__device__ __forceinline__ void attn_body(const f16* __restrict__ qkv, f16* __restrict__ ao,
                                          int tokoff, int bh,
                                          f16* __restrict__ Ks, f16* __restrict__ Vt,
                                          f16* __restrict__ Pl) {
  const int b = bh / HEADS, h = bh % HEADS;
  const int tid = threadIdx.x, lane = tid & 63, wid = tid >> 6;
  const int l15 = lane & 15, lg = lane >> 4;
  const size_t base = (size_t)(tokoff + b * S) * (3 * DD) + (size_t)h * DH;
  const f16* qg = qkv + base;
  const f16* kg = qkv + base + DD;
  const f16* vg = qkv + base + 2 * DD;

  for (int c = tid; c < S * 8; c += 256) {
    const int row = c >> 3, off = (c & 7) * 8;
    *(h8*)&Ks[row * KSTR + off] = *(const h8*)&kg[(size_t)row * (3 * DD) + off];
    const h8 vv = *(const h8*)&vg[(size_t)row * (3 * DD) + off];
    #pragma unroll
    for (int j = 0; j < 8; ++j) Vt[(off + j) * VSTR + row] = vv[j];
  }
  __syncthreads();

  for (int qt = wid; qt < S / 16; qt += 4) {
    const int q0 = qt * 16;
    h8 aq[2];
    #pragma unroll
    for (int s = 0; s < 2; ++s)
      aq[s] = *(const h8*)&qg[(size_t)(q0 + l15) * (3 * DD) + s * 32 + lg * 8];

    f32x4 sc[S / 16];
    #pragma unroll
    for (int kt = 0; kt < S / 16; ++kt) {
      f32x4 c = {};
      const h8 b0 = *(const h8*)&Ks[(kt * 16 + l15) * KSTR + lg * 8];
      const h8 b1 = *(const h8*)&Ks[(kt * 16 + l15) * KSTR + 32 + lg * 8];
      c = __builtin_amdgcn_mfma_f32_16x16x32_f16(aq[0], b0, c, 0, 0, 0);
      c = __builtin_amdgcn_mfma_f32_16x16x32_f16(aq[1], b1, c, 0, 0, 0);
      sc[kt] = c;
    }
    float mx[4], zz[4];
    #pragma unroll
    for (int r = 0; r < 4; ++r) {
      float m = -1e30f;
      #pragma unroll
      for (int kt = 0; kt < S / 16; ++kt) m = fmaxf(m, sc[kt][r]);
      #pragma unroll
      for (int o = 1; o < 16; o <<= 1) m = fmaxf(m, __shfl_xor(m, o));
      mx[r] = m; zz[r] = 0.f;
    }
    #pragma unroll
    for (int kt = 0; kt < S / 16; ++kt)
      #pragma unroll
      for (int r = 0; r < 4; ++r) {
        const float p = __expf((sc[kt][r] - mx[r]) * 0.125f);
        zz[r] += p;
        Pl[(wid * 16 + lg * 4 + r) * VSTR + kt * 16 + l15] = (f16)p;
      }
    #pragma unroll
    for (int r = 0; r < 4; ++r) {
      #pragma unroll
      for (int o = 1; o < 16; o <<= 1) zz[r] += __shfl_xor(zz[r], o);
      zz[r] = 1.f / zz[r];
    }
    // Pl is wave-private; same-wave LDS ordering, no barrier needed.
    f32x4 o4[4] = {};
    #pragma unroll
    for (int ks = 0; ks < S / 32; ++ks) {
      const h8 pa = *(const h8*)&Pl[(wid * 16 + l15) * VSTR + ks * 32 + lg * 8];
      #pragma unroll
      for (int n = 0; n < 4; ++n) {
        const h8 bv_ = *(const h8*)&Vt[(n * 16 + l15) * VSTR + ks * 32 + lg * 8];
        o4[n] = __builtin_amdgcn_mfma_f32_16x16x32_f16(pa, bv_, o4[n], 0, 0, 0);
      }
    }
    #pragma unroll
    for (int n = 0; n < 4; ++n)
      #pragma unroll
      for (int r = 0; r < 4; ++r) {
        const int row = q0 + lg * 4 + r;
        ao[(size_t)(tokoff + b * S + row) * DD + h * DH + n * 16 + l15] = (f16)(o4[n][r] * zz[r]);
      }
  }
}

__launch_bounds__(256)
__global__ void attn_all_kernel(const f16* __restrict__ qkv, f16* __restrict__ ao) {
  // carve: Ks 256*88=22528 | Vt 64*264=16896 | Pl 4*16*264=16896  (f16)
  __shared__ __align__(16) f16 smem[56320];
  f16* Ks = smem;
  f16* Vt = smem + 22528;
  f16* Pl = smem + 22528 + 16896;
  const int bx = blockIdx.x;
  if (bx < NB * HEADS) attn_body<256>(qkv, ao, 0, bx, Ks, Vt, Pl);
  else                 attn_body<128>(qkv, ao, NCTX, bx - NB * HEADS, Ks, Vt, Pl);
}

// ---------------- vectorized LN kernels (192 threads, h4 = 8B/lane) ----------------
__launch_bounds__(192)
__global__ void pos_ln16v(const f16* __restrict__ tmp, const float* __restrict__ pos,
                          const float* __restrict__ g, const float* __restrict__ be,
                          f16* __restrict__ out) {
  __shared__ float red[3];
  const int tok = blockIdx.x;
  const int s = (tok < NCTX) ? (tok & 255) : (tok & 127);
  const size_t row = (size_t)tok * DD;
  const int j = threadIdx.x * 4;
  const h4 a = *(const h4*)&tmp[row + j];
  const float4 p = *(const float4*)&pos[(size_t)s * DD + j];
  float x[4] = { (float)a[0] + p.x, (float)a[1] + p.y, (float)a[2] + p.z, (float)a[3] + p.w };
  float sm = 0.f, ss = 0.f;
  #pragma unroll
  for (int i = 0; i < 4; ++i) { sm += x[i]; ss += x[i] * x[i]; }
  sm = block_reduce_sum3(sm, red);
  ss = block_reduce_sum3(ss, red);
  const float mean = sm * (1.f / DD);
  const float inv = rsqrtf(ss * (1.f / DD) - mean * mean + 1e-12f);
  const float4 gv = *(const float4*)&g[j];
  const float4 bv = *(const float4*)&be[j];
  h4 o;
  o[0] = (f16)((x[0] - mean) * inv * gv.x + bv.x);
  o[1] = (f16)((x[1] - mean) * inv * gv.y + bv.y);
  o[2] = (f16)((x[2] - mean) * inv * gv.z + bv.z);
  o[3] = (f16)((x[3] - mean) * inv * gv.w + bv.w);
  *(h4*)&out[row + j] = o;
}

template<int ND>
__launch_bounds__(192)
__global__ void add_ln16v(const f16* __restrict__ hin, const f16* __restrict__ d0,
                          const f16* __restrict__ d1,
                          const float* __restrict__ g, const float* __restrict__ be,
                          f16* __restrict__ out) {
  __shared__ float red[3];
  const size_t row = (size_t)blockIdx.x * DD;
  const int j = threadIdx.x * 4;
  const h4 a = *(const h4*)&hin[row + j];
  const h4 b = *(const h4*)&d0[row + j];
  h4 c = {};
  if (ND == 2) c = *(const h4*)&d1[row + j];
  float x[4]; float sm = 0.f, ss = 0.f;
  #pragma unroll
  for (int i = 0; i < 4; ++i) {
    float v = (float)a[i] + (float)b[i];
    if (ND == 2) v += (float)c[i];
    x[i] = v; sm += v; ss += v * v;
  }
  sm = block_reduce_sum3(sm, red);
  ss = block_reduce_sum3(ss, red);
  const float mean = sm * (1.f / DD);
  const float inv = rsqrtf(ss * (1.f / DD) - mean * mean + 1e-12f);
  const float4 gv = *(const float4*)&g[j];
  const float4 bv = *(const float4*)&be[j];
  h4 o;
  o[0] = (f16)((x[0] - mean) * inv * gv.x + bv.x);
  o[1] = (f16)((x[1] - mean) * inv * gv.y + bv.y);
  o[2] = (f16)((x[2] - mean) * inv * gv.z + bv.z);
  o[3] = (f16)((x[3] - mean) * inv * gv.w + bv.w);
  *(h4*)&out[row + j] = o;
}

// ---------------- final cosine reduction ----------------
struct OutsF16 { const f16* p[4]; };

__launch_bounds__(256)
__global__ void invnorm16_kernel(OutsF16 o4, float* __restrict__ invn) {
  __shared__ float red[4];
  const size_t row = (size_t)blockIdx.x * DD;
  float ss = 0.f;
  #pragma unroll
  for (int l = 0; l < 4; ++l)
    #pragma unroll
    for (int i = 0; i < 3; ++i) {
      const float v = (float)o4.p[l][row + threadIdx.x + (i << 8)];
      ss += v * v;
    }
  ss = block_reduce_sum(ss, red);
  if (threadIdx.x == 0) invn[blockIdx.x] = 1.f / fmaxf(sqrtf(ss), 1e-8f);
}

__launch_bounds__(256)
__global__ void normsum16_kernel(OutsF16 o4, const float* __restrict__ invn,
                                 float* __restrict__ accC, float* __restrict__ accA) {
  const int b = blockIdx.x;
  const int l = blockIdx.y / 3;
  const int j = (blockIdx.y % 3) * 256 + threadIdx.x;
  const int pass = blockIdx.z;
  const int S = pass ? 128 : 256;
  const int tb = pass ? (NCTX + b * 128) : (b * 256);
  float* acc = pass ? accA : accC;
  const f16* __restrict__ src = o4.p[l];
  float s = 0.f;
  for (int si = 0; si < S; ++si)
    s = fmaf((float)src[(size_t)(tb + si) * DD + j], invn[tb + si], s);
  acc[(size_t)b * (4 * DD) + (size_t)l * DD + j] = s;
}

__launch_bounds__(256)
__global__ void final_dot_kernel(const float* __restrict__ a, const float* __restrict__ c,
                                 float* __restrict__ out) {
  __shared__ float red[4];
  const size_t base = (size_t)blockIdx.x * (4 * DD);
  float s = 0.f;
  #pragma unroll
  for (int i = 0; i < 12; ++i) {
    const int j = threadIdx.x + (i << 8);
    s = fmaf(a[base + j], c[base + j], s);
  }
  s = block_reduce_sum(s, red);
  if (threadIdx.x == 0) out[blockIdx.x] = s;
}

// ---------------- host orchestration ----------------
extern "C" void kernel_launch(void* const* d_in, const int* in_sizes, int n_in,
                              void* d_out, int out_size, void* d_ws, size_t ws_size,
                              hipStream_t stream) {
  (void)in_sizes; (void)n_in; (void)out_size; (void)ws_size;
  const float* ctx   = (const float*)d_in[0];
  const float* asp   = (const float*)d_in[1];
  const float* fc1_w = (const float*)d_in[2];
  const float* fc1_b = (const float*)d_in[3];
  const float* pos   = (const float*)d_in[4];
  const float* emb_g = (const float*)d_in[5];
  const float* emb_b = (const float*)d_in[6];
  const float* Wq    = (const float*)d_in[7];
  const float* bq    = (const float*)d_in[8];
  const float* Wk    = (const float*)d_in[9];
  const float* bk    = (const float*)d_in[10];
  const float* Wv    = (const float*)d_in[11];
  const float* bv    = (const float*)d_in[12];
  const float* Wo    = (const float*)d_in[13];
  const float* bo    = (const float*)d_in[14];
  const float* ln1g  = (const float*)d_in[15];
  const float* ln1b  = (const float*)d_in[16];
  const float* W1    = (const float*)d_in[17];
  const float* bf1   = (const float*)d_in[18];
  const float* W2    = (const float*)d_in[19];
  const float* bf2   = (const float*)d_in[20];
  const float* ln2g  = (const float*)d_in[21];
  const float* ln2b  = (const float*)d_in[22];
  float* out = (float*)d_out;

  // ---- workspace carving (all-f16 activations) ----
  f16* f = (f16*)d_ws;
  size_t o = 0;
  f16* fc1T  = f + o; o += (size_t)DD * KPAD;
  f16* WqkvT = f + o; o += (size_t)NLAYER * 3 * DD * DD;
  f16* WoT   = f + o; o += (size_t)NLAYER * DD * DD;
  f16* W1T   = f + o; o += (size_t)NLAYER * FFD * DD;
  f16* W2T   = f + o; o += (size_t)NLAYER * DD * FFD;
  f16* R     = f + o; o += (size_t)NALL * FFD;     // alias: xpad | qkv+ao | mid
  f16* tmp16 = f + o; o += (size_t)NALL * DD;
  f16* h0f16 = f + o; o += (size_t)NALL * DD;
  f16* hmf16 = f + o; o += (size_t)NALL * DD;
  f16* pp    = f + o; o += (size_t)2 * NALL * DD;  // split-K partials (Wo, FF2)
  f16* outs16[4];
  for (int l = 0; l < 4; ++l) { outs16[l] = f + o; o += (size_t)NALL * DD; }

  f16* xpad = R;
  f16* qkv  = R;
  f16* ao   = R + (size_t)NALL * 3 * DD;
  f16* mid  = R;

  float* g32 = (float*)(f + o);
  size_t o2 = 0;
  float* bqkv = g32 + o2; o2 += (size_t)NLAYER * 3 * DD;
  float* accC = g32 + o2; o2 += (size_t)NB * 4 * DD;
  float* accA = g32 + o2; o2 += (size_t)NB * 4 * DD;
  float* invn = g32 + o2; o2 += NALL;

  // ---- weight prep (z-batched) ----
  transpose_cast_kernel<<<dim3(KPAD / 32, DD / 32, 1), 256, 0, stream>>>(
      fc1_w, fc1T, EMBD, DD, KPAD, 0, 0);
  transpose_cast_kernel<<<dim3(DD / 32, DD / 32, NLAYER), 256, 0, stream>>>(
      Wq, WqkvT, DD, DD, DD, (size_t)DD * DD, (size_t)3 * DD * DD);
  transpose_cast_kernel<<<dim3(DD / 32, DD / 32, NLAYER), 256, 0, stream>>>(
      Wk, WqkvT + (size_t)DD * DD, DD, DD, DD, (size_t)DD * DD, (size_t)3 * DD * DD);
  transpose_cast_kernel<<<dim3(DD / 32, DD / 32, NLAYER), 256, 0, stream>>>(
      Wv, WqkvT + (size_t)2 * DD * DD, DD, DD, DD, (size_t)DD * DD, (size_t)3 * DD * DD);
  transpose_cast_kernel<<<dim3(DD / 32, DD / 32, NLAYER), 256, 0, stream>>>(
      Wo, WoT, DD, DD, DD, (size_t)DD * DD, (size_t)DD * DD);
  transpose_cast_kernel<<<dim3(DD / 32, FFD / 32, NLAYER), 256, 0, stream>>>(
      W1, W1T, DD, FFD, DD, (size_t)DD * FFD, (size_t)FFD * DD);
  transpose_cast_kernel<<<dim3(FFD / 32, DD / 32, NLAYER), 256, 0, stream>>>(
      W2, W2T, FFD, DD, FFD, (size_t)FFD * DD, (size_t)DD * FFD);
  bias_concat_kernel<<<NLAYER, 256, 0, stream>>>(bq, bk, bv, bqkv);

  // ---- merged encoder over 6144 tokens ----
  castpad_kernel<<<NALL, 256, 0, stream>>>(ctx, asp, xpad);
  gemm_w512<KPAD, 1, 0><<<dim3(NALL / 128, DD / 128), 512, 0, stream>>>(
      xpad, fc1T, fc1_b, tmp16, DD);
  pos_ln16v<<<NALL, 192, 0, stream>>>(tmp16, pos, emb_g, emb_b, h0f16);

  const f16* hin16 = h0f16;
  for (int l = 0; l < NLAYER; ++l) {
    gemm_w512<DD, 1, 0><<<dim3(NALL / 128, (3 * DD) / 128), 512, 0, stream>>>(
        hin16, WqkvT + (size_t)l * 3 * DD * DD, bqkv + l * 3 * DD, qkv, 3 * DD);
    attn_all_kernel<<<2 * NB * HEADS, 256, 0, stream>>>(qkv, ao);
    gemm_w512<DD, 2, 0><<<dim3(NALL / 128, DD / 128, 2), 512, 0, stream>>>(
        ao, WoT + (size_t)l * DD * DD, bo + l * DD, pp, DD);
    add_ln16v<2><<<NALL, 192, 0, stream>>>(hin16, pp, pp + (size_t)NALL * DD,
                                           ln1g + l * DD, ln1b + l * DD, hmf16);
    gemm_w512<DD, 1, 1><<<dim3(NALL / 128, FFD / 128), 512, 0, stream>>>(
        hmf16, W1T + (size_t)l * FFD * DD, bf1 + l * FFD, mid, FFD);
    gemm_w512<FFD, 2, 0><<<dim3(NALL / 128, DD / 128, 2), 512, 0, stream>>>(
        mid, W2T + (size_t)l * DD * FFD, bf2 + l * DD, pp, DD);
    add_ln16v<2><<<NALL, 192, 0, stream>>>(hmf16, pp, pp + (size_t)NALL * DD,
                                           ln2g + l * DD, ln2b + l * DD, outs16[l]);
    hin16 = outs16[l];
  }

  OutsF16 o4;
  for (int i = 0; i < 4; ++i) o4.p[i] = outs16[i];
  invnorm16_kernel<<<NALL, 256, 0, stream>>>(o4, invn);
  normsum16_kernel<<<dim3(NB, 12, 2), 256, 0, stream>>>(o4, invn, accC, accA);
  final_dot_kernel<<<NB, 256, 0, stream>>>(accA, accC, out);
}

// Round 16
// 854.119 us; speedup vs baseline: 1.7326x; 1.0606x over previous
//
#include <hip/hip_runtime.h>
#include <math.h>

typedef _Float16 f16;
typedef _Float16 h8 __attribute__((ext_vector_type(8)));
typedef _Float16 h4 __attribute__((ext_vector_type(4)));
typedef float f32x4 __attribute__((ext_vector_type(4)));

#define HEADS 12
#define DH 64
#define DD 768
#define FFD 3072
#define EMBD 300
#define KPAD 384
#define NLAYER 4
#define NB 16
#define NCTX 4096           // 16 * 256
#define NALL 6144           // 16*256 + 16*128
#define NSPLIT 8            // si-splits for normsum partials

// ---------------- block reductions ----------------
__device__ __forceinline__ float block_reduce_sum(float v, float* red) {
  #pragma unroll
  for (int o = 32; o; o >>= 1) v += __shfl_xor(v, o);
  const int wid = threadIdx.x >> 6;
  __syncthreads();
  if ((threadIdx.x & 63) == 0) red[wid] = v;
  __syncthreads();
  float r = red[0];
  #pragma unroll
  for (int w = 1; w < 4; ++w) r += red[w];
  return r;
}

__device__ __forceinline__ float block_reduce_sum3(float v, float* red) {
  #pragma unroll
  for (int o = 32; o; o >>= 1) v += __shfl_xor(v, o);
  const int wid = threadIdx.x >> 6;
  __syncthreads();
  if ((threadIdx.x & 63) == 0) red[wid] = v;
  __syncthreads();
  return red[0] + red[1] + red[2];
}

// ---------------- async global->LDS 16B ----------------
__device__ __forceinline__ void gload16(const f16* g, f16* lds) {
  __builtin_amdgcn_global_load_lds(
      (const __attribute__((address_space(1))) unsigned int*)g,
      (__attribute__((address_space(3))) unsigned int*)lds, 16, 0, 0);
}

// ---------------- weight transpose + cast (z-batched) ----------------
__launch_bounds__(256)
__global__ void transpose_cast_kernel(const float* __restrict__ W, f16* __restrict__ Wt,
                                      int K, int M, int Kpad,
                                      size_t srcStride, size_t dstStride) {
  W += (size_t)blockIdx.z * srcStride;
  Wt += (size_t)blockIdx.z * dstStride;
  __shared__ float t[32][33];
  const int k0 = blockIdx.x * 32, m0 = blockIdx.y * 32;
  const int c = threadIdx.x & 31, r8 = threadIdx.x >> 5;
  #pragma unroll
  for (int p = 0; p < 4; ++p) {
    const int k = k0 + r8 + p * 8;
    t[r8 + p * 8][c] = (k < K && m0 + c < M) ? W[(size_t)k * M + m0 + c] : 0.f;
  }
  __syncthreads();
  #pragma unroll
  for (int p = 0; p < 4; ++p) {
    const int m = m0 + r8 + p * 8;
    const int k = k0 + c;
    if (m < M && k < Kpad) Wt[(size_t)m * Kpad + k] = (f16)t[c][r8 + p * 8];
  }
}

__launch_bounds__(256)
__global__ void castpad_kernel(const float* __restrict__ ctx, const float* __restrict__ asp,
                               f16* __restrict__ xp) {
  const int tok = blockIdx.x;
  const float* src;
  int r;
  if (tok < NCTX) { src = ctx; r = tok; } else { src = asp; r = tok - NCTX; }
  for (int j = threadIdx.x; j < KPAD; j += 256)
    xp[(size_t)tok * KPAD + j] = (j < EMBD) ? (f16)src[(size_t)r * EMBD + j] : (f16)0.f;
}

__launch_bounds__(256)
__global__ void bias_concat_kernel(const float* __restrict__ bq, const float* __restrict__ bk,
                                   const float* __restrict__ bv, float* __restrict__ bqkv) {
  const int l = blockIdx.x;
  for (int j = threadIdx.x; j < DD; j += 256) {
    bqkv[l * 3 * DD + j] = bq[l * DD + j];
    bqkv[l * 3 * DD + DD + j] = bk[l * DD + j];
    bqkv[l * 3 * DD + 2 * DD + j] = bv[l * DD + j];
  }
}

// ======== 128x128 f16 GEMM, 512 threads / 8 waves (2Mx4N), 3-buffer 2-ahead ========
#define GBK 32

template<int K, int KSPLIT, int ACT>
__launch_bounds__(512, 6)
__global__ void gemm_w512(const f16* __restrict__ A, const f16* __restrict__ Bt,
                          const float* __restrict__ bias, f16* __restrict__ C, int M) {
  constexpr int KB = K / KSPLIT;
  constexpr int NSTEP = KB / GBK;
  static_assert(NSTEP >= 3, "need >=3 K-steps");
  __shared__ __align__(16) f16 As[3][128 * GBK];
  __shared__ __align__(16) f16 Bs[3][128 * GBK];
  const int tid = threadIdx.x, lane = tid & 63, wid = tid >> 6;
  const int wr = (wid >> 2) * 64, wc = (wid & 3) * 32;
  const int l15 = lane & 15, lg = lane >> 4;

  const int bm = blockIdx.x * 128;
  const int bn = blockIdx.y * 128;
  const int kb0 = (KSPLIT > 1) ? blockIdx.z * KB : 0;

  const int v0 = tid & 255, v1 = v0 + 256;
  const int r0 = v0 >> 2, s0 = v0 & 3;
  const int r1 = v1 >> 2, s1 = v1 & 3;
  const int gc0 = (s0 ^ ((r0 >> 1) & 3)) * 8;
  const int gc1 = (s1 ^ ((r1 >> 1) & 3)) * 8;
  const bool isA = (wid < 4);
  const f16* gsrc0 = isA ? A + (size_t)(bm + r0) * K + kb0 + gc0
                         : Bt + (size_t)(bn + r0) * K + kb0 + gc0;
  const f16* gsrc1 = isA ? A + (size_t)(bm + r1) * K + kb0 + gc1
                         : Bt + (size_t)(bn + r1) * K + kb0 + gc1;
  f16* dst0[3]; f16* dst1[3];
  #pragma unroll
  for (int b = 0; b < 3; ++b) {
    dst0[b] = isA ? &As[b][((wid & 3) * 64) * 8]         : &Bs[b][((wid & 3) * 64) * 8];
    dst1[b] = isA ? &As[b][(256 + (wid & 3) * 64) * 8]   : &Bs[b][(256 + (wid & 3) * 64) * 8];
  }

  f32x4 acc[4][2] = {};

  gload16(gsrc0, dst0[0]);
  gload16(gsrc1, dst1[0]);
  gload16(gsrc0 + GBK, dst0[1]);
  gload16(gsrc1 + GBK, dst1[1]);

  int b3 = 0;
  for (int t = 0; t < NSTEP; ++t) {
    if (t + 1 < NSTEP) asm volatile("s_waitcnt vmcnt(2)" ::: "memory");
    else               asm volatile("s_waitcnt vmcnt(0)" ::: "memory");
    __builtin_amdgcn_s_barrier();
    if (t + 2 < NSTEP) {
      const int sn = (b3 + 2 >= 3) ? b3 - 1 : b3 + 2;
      gload16(gsrc0 + (t + 2) * GBK, dst0[sn]);
      gload16(gsrc1 + (t + 2) * GBK, dst1[sn]);
    }
    h8 af[4], bf[2];
    #pragma unroll
    for (int m = 0; m < 4; ++m) {
      const int row = wr + m * 16 + l15;
      af[m] = *(const h8*)&As[b3][(row * 4 + (lg ^ ((row >> 1) & 3))) * 8];
    }
    #pragma unroll
    for (int n = 0; n < 2; ++n) {
      const int row = wc + n * 16 + l15;
      bf[n] = *(const h8*)&Bs[b3][(row * 4 + (lg ^ ((row >> 1) & 3))) * 8];
    }
    #pragma unroll
    for (int m = 0; m < 4; ++m)
      #pragma unroll
      for (int n = 0; n < 2; ++n)
        acc[m][n] = __builtin_amdgcn_mfma_f32_16x16x32_f16(af[m], bf[n], acc[m][n], 0, 0, 0);
    b3 = (b3 + 1 >= 3) ? 0 : b3 + 1;
  }

  f16* Co = C + ((KSPLIT > 1) ? (size_t)blockIdx.z * NALL * M : (size_t)0);
  #pragma unroll
  for (int m = 0; m < 4; ++m) {
    #pragma unroll
    for (int n = 0; n < 2; ++n) {
      #pragma unroll
      for (int r = 0; r < 4; ++r) {
        const int row = bm + wr + m * 16 + lg * 4 + r;
        const int col = bn + wc + n * 16 + l15;
        float vv = acc[m][n][r];
        if (KSPLIT == 1 || blockIdx.z == 0) vv += bias[col];
        if (ACT == 1) {
          const float u = 1.5957691216057308f * (vv + 0.044715f * vv * vv * vv);
          vv = vv / (1.f + __expf(-u));
        }
        Co[(size_t)row * M + col] = (f16)vv;
      }
    }
  }
}

// ---------------- MFMA attention: merged ctx+asp, one dispatch ----------------
#define KSTR 88
#define VSTR 264

template<int S>
__device__ __forceinline__ void attn_body(const f16* __restrict__ qkv, f16* __restrict__ ao,
                                          int tokoff, int bh,
                                          f16* __restrict__ Ks, f16* __restrict__ Vt,
                                          f16* __restrict__ Pl) {
  const int b = bh / HEADS, h = bh % HEADS;
  const int tid = threadIdx.x, lane = tid & 63, wid = tid >> 6;
  const int l15 = lane & 15, lg = lane >> 4;
  const size_t base = (size_t)(tokoff + b * S) * (3 * DD) + (size_t)h * DH;
  const f16* qg = qkv + base;
  const f16* kg = qkv + base + DD;
  const f16* vg = qkv + base + 2 * DD;

  for (int c = tid; c < S * 8; c += 256) {
    const int row = c >> 3, off = (c & 7) * 8;
    *(h8*)&Ks[row * KSTR + off] = *(const h8*)&kg[(size_t)row * (3 * DD) + off];
    const h8 vv = *(const h8*)&vg[(size_t)row * (3 * DD) + off];
    #pragma unroll
    for (int j = 0; j < 8; ++j) Vt[(off + j) * VSTR + row] = vv[j];
  }
  __syncthreads();

  for (int qt = wid; qt < S / 16; qt += 4) {
    const int q0 = qt * 16;
    h8 aq[2];
    #pragma unroll
    for (int s = 0; s < 2; ++s)
      aq[s] = *(const h8*)&qg[(size_t)(q0 + l15) * (3 * DD) + s * 32 + lg * 8];

    f32x4 sc[S / 16];
    #pragma unroll
    for (int kt = 0; kt < S / 16; ++kt) {
      f32x4 c = {};
      const h8 b0 = *(const h8*)&Ks[(kt * 16 + l15) * KSTR + lg * 8];
      const h8 b1 = *(const h8*)&Ks[(kt * 16 + l15) * KSTR + 32 + lg * 8];
      c = __builtin_amdgcn_mfma_f32_16x16x32_f16(aq[0], b0, c, 0, 0, 0);
      c = __builtin_amdgcn_mfma_f32_16x16x32_f16(aq[1], b1, c, 0, 0, 0);
      sc[kt] = c;
    }
    float mx[4], zz[4];
    #pragma unroll
    for (int r = 0; r < 4; ++r) {
      float m = -1e30f;
      #pragma unroll
      for (int kt = 0; kt < S / 16; ++kt) m = fmaxf(m, sc[kt][r]);
      #pragma unroll
      for (int o = 1; o < 16; o <<= 1) m = fmaxf(m, __shfl_xor(m, o));
      mx[r] = m; zz[r] = 0.f;
    }
    #pragma unroll
    for (int kt = 0; kt < S / 16; ++kt)
      #pragma unroll
      for (int r = 0; r < 4; ++r) {
        const float p = __expf((sc[kt][r] - mx[r]) * 0.125f);
        zz[r] += p;
        Pl[(wid * 16 + lg * 4 + r) * VSTR + kt * 16 + l15] = (f16)p;
      }
    #pragma unroll
    for (int r = 0; r < 4; ++r) {
      #pragma unroll
      for (int o = 1; o < 16; o <<= 1) zz[r] += __shfl_xor(zz[r], o);
      zz[r] = 1.f / zz[r];
    }
    // Pl is wave-private; same-wave LDS ordering, no barrier needed.
    f32x4 o4[4] = {};
    #pragma unroll
    for (int ks = 0; ks < S / 32; ++ks) {
      const h8 pa = *(const h8*)&Pl[(wid * 16 + l15) * VSTR + ks * 32 + lg * 8];
      #pragma unroll
      for (int n = 0; n < 4; ++n) {
        const h8 bv_ = *(const h8*)&Vt[(n * 16 + l15) * VSTR + ks * 32 + lg * 8];
        o4[n] = __builtin_amdgcn_mfma_f32_16x16x32_f16(pa, bv_, o4[n], 0, 0, 0);
      }
    }
    #pragma unroll
    for (int n = 0; n < 4; ++n)
      #pragma unroll
      for (int r = 0; r < 4; ++r) {
        const int row = q0 + lg * 4 + r;
        ao[(size_t)(tokoff + b * S + row) * DD + h * DH + n * 16 + l15] = (f16)(o4[n][r] * zz[r]);
      }
  }
}

__launch_bounds__(256)
__global__ void attn_all_kernel(const f16* __restrict__ qkv, f16* __restrict__ ao) {
  __shared__ __align__(16) f16 smem[56320];
  f16* Ks = smem;
  f16* Vt = smem + 22528;
  f16* Pl = smem + 22528 + 16896;
  const int bx = blockIdx.x;
  if (bx < NB * HEADS) attn_body<256>(qkv, ao, 0, bx, Ks, Vt, Pl);
  else                 attn_body<128>(qkv, ao, NCTX, bx - NB * HEADS, Ks, Vt, Pl);
}

// ---------------- vectorized LN kernels (192 threads, h4 = 8B/lane) ----------------
__launch_bounds__(192)
__global__ void pos_ln16v(const f16* __restrict__ tmp, const float* __restrict__ pos,
                          const float* __restrict__ g, const float* __restrict__ be,
                          f16* __restrict__ out) {
  __shared__ float red[3];
  const int tok = blockIdx.x;
  const int s = (tok < NCTX) ? (tok & 255) : (tok & 127);
  const size_t row = (size_t)tok * DD;
  const int j = threadIdx.x * 4;
  const h4 a = *(const h4*)&tmp[row + j];
  const float4 p = *(const float4*)&pos[(size_t)s * DD + j];
  float x[4] = { (float)a[0] + p.x, (float)a[1] + p.y, (float)a[2] + p.z, (float)a[3] + p.w };
  float sm = 0.f, ss = 0.f;
  #pragma unroll
  for (int i = 0; i < 4; ++i) { sm += x[i]; ss += x[i] * x[i]; }
  sm = block_reduce_sum3(sm, red);
  ss = block_reduce_sum3(ss, red);
  const float mean = sm * (1.f / DD);
  const float inv = rsqrtf(ss * (1.f / DD) - mean * mean + 1e-12f);
  const float4 gv = *(const float4*)&g[j];
  const float4 bv = *(const float4*)&be[j];
  h4 o;
  o[0] = (f16)((x[0] - mean) * inv * gv.x + bv.x);
  o[1] = (f16)((x[1] - mean) * inv * gv.y + bv.y);
  o[2] = (f16)((x[2] - mean) * inv * gv.z + bv.z);
  o[3] = (f16)((x[3] - mean) * inv * gv.w + bv.w);
  *(h4*)&out[row + j] = o;
}

template<int ND>
__launch_bounds__(192)
__global__ void add_ln16v(const f16* __restrict__ hin, const f16* __restrict__ d0,
                          const f16* __restrict__ d1,
                          const float* __restrict__ g, const float* __restrict__ be,
                          f16* __restrict__ out) {
  __shared__ float red[3];
  const size_t row = (size_t)blockIdx.x * DD;
  const int j = threadIdx.x * 4;
  const h4 a = *(const h4*)&hin[row + j];
  const h4 b = *(const h4*)&d0[row + j];
  h4 c = {};
  if (ND == 2) c = *(const h4*)&d1[row + j];
  float x[4]; float sm = 0.f, ss = 0.f;
  #pragma unroll
  for (int i = 0; i < 4; ++i) {
    float v = (float)a[i] + (float)b[i];
    if (ND == 2) v += (float)c[i];
    x[i] = v; sm += v; ss += v * v;
  }
  sm = block_reduce_sum3(sm, red);
  ss = block_reduce_sum3(ss, red);
  const float mean = sm * (1.f / DD);
  const float inv = rsqrtf(ss * (1.f / DD) - mean * mean + 1e-12f);
  const float4 gv = *(const float4*)&g[j];
  const float4 bv = *(const float4*)&be[j];
  h4 o;
  o[0] = (f16)((x[0] - mean) * inv * gv.x + bv.x);
  o[1] = (f16)((x[1] - mean) * inv * gv.y + bv.y);
  o[2] = (f16)((x[2] - mean) * inv * gv.z + bv.z);
  o[3] = (f16)((x[3] - mean) * inv * gv.w + bv.w);
  *(h4*)&out[row + j] = o;
}

// ---------------- final cosine reduction ----------------
struct OutsF16 { const f16* p[4]; };

__launch_bounds__(192)
__global__ void invnorm16v(OutsF16 o4, float* __restrict__ invn) {
  __shared__ float red[3];
  const size_t row = (size_t)blockIdx.x * DD;
  const int j = threadIdx.x * 4;
  float ss = 0.f;
  #pragma unroll
  for (int l = 0; l < 4; ++l) {
    const h4 v = *(const h4*)&o4.p[l][row + j];
    #pragma unroll
    for (int i = 0; i < 4; ++i) { const float f = (float)v[i]; ss += f * f; }
  }
  ss = block_reduce_sum3(ss, red);
  if (threadIdx.x == 0) invn[blockIdx.x] = 1.f / fmaxf(sqrtf(ss), 1e-8f);
}

// normsum partials: part[s][b][(pass*4+l)*DD + j] = sum over this split's tokens
__launch_bounds__(192)
__global__ void normsum16p(OutsF16 o4, const float* __restrict__ invn,
                           float* __restrict__ part) {
  const int b = blockIdx.x;
  const int y = blockIdx.y;            // pass*4 + l
  const int pass = y >> 2, l = y & 3;
  const int s = blockIdx.z;
  const int S = pass ? 128 : 256;
  const int tb = pass ? (NCTX + b * 128) : (b * 256);
  const int chunk = S / NSPLIT;
  const int si0 = s * chunk;
  const f16* __restrict__ src = o4.p[l];
  const int j = threadIdx.x * 4;
  float a0 = 0.f, a1 = 0.f, a2 = 0.f, a3 = 0.f;
  for (int si = si0; si < si0 + chunk; ++si) {
    const float w = invn[tb + si];
    const h4 v = *(const h4*)&src[(size_t)(tb + si) * DD + j];
    a0 = fmaf((float)v[0], w, a0);
    a1 = fmaf((float)v[1], w, a1);
    a2 = fmaf((float)v[2], w, a2);
    a3 = fmaf((float)v[3], w, a3);
  }
  float* dst = part + ((size_t)s * NB + b) * (8 * DD) + (size_t)y * DD + j;
  dst[0] = a0; dst[1] = a1; dst[2] = a2; dst[3] = a3;
}

__launch_bounds__(256)
__global__ void final_dot2(const float* __restrict__ part, float* __restrict__ out) {
  __shared__ float red[4];
  const int b = blockIdx.x;
  float sum = 0.f;
  #pragma unroll
  for (int i = 0; i < 12; ++i) {
    const int p = threadIdx.x + (i << 8);     // p in [0, 4*DD)
    float cs = 0.f, as_ = 0.f;
    #pragma unroll
    for (int s = 0; s < NSPLIT; ++s) {
      const float* base = part + ((size_t)s * NB + b) * (8 * DD);
      cs  += base[p];            // ctx (pass 0): y in 0..3
      as_ += base[4 * DD + p];   // asp (pass 1): y in 4..7
    }
    sum = fmaf(as_, cs, sum);
  }
  sum = block_reduce_sum(sum, red);
  if (threadIdx.x == 0) out[b] = sum;
}

// ---------------- host orchestration ----------------
extern "C" void kernel_launch(void* const* d_in, const int* in_sizes, int n_in,
                              void* d_out, int out_size, void* d_ws, size_t ws_size,
                              hipStream_t stream) {
  (void)in_sizes; (void)n_in; (void)out_size; (void)ws_size;
  const float* ctx   = (const float*)d_in[0];
  const float* asp   = (const float*)d_in[1];
  const float* fc1_w = (const float*)d_in[2];
  const float* fc1_b = (const float*)d_in[3];
  const float* pos   = (const float*)d_in[4];
  const float* emb_g = (const float*)d_in[5];
  const float* emb_b = (const float*)d_in[6];
  const float* Wq    = (const float*)d_in[7];
  const float* bq    = (const float*)d_in[8];
  const float* Wk    = (const float*)d_in[9];
  const float* bk    = (const float*)d_in[10];
  const float* Wv    = (const float*)d_in[11];
  const float* bv    = (const float*)d_in[12];
  const float* Wo    = (const float*)d_in[13];
  const float* bo    = (const float*)d_in[14];
  const float* ln1g  = (const float*)d_in[15];
  const float* ln1b  = (const float*)d_in[16];
  const float* W1    = (const float*)d_in[17];
  const float* bf1   = (const float*)d_in[18];
  const float* W2    = (const float*)d_in[19];
  const float* bf2   = (const float*)d_in[20];
  const float* ln2g  = (const float*)d_in[21];
  const float* ln2b  = (const float*)d_in[22];
  float* out = (float*)d_out;

  // ---- workspace carving (all-f16 activations) ----
  f16* f = (f16*)d_ws;
  size_t o = 0;
  f16* fc1T  = f + o; o += (size_t)DD * KPAD;
  f16* WqkvT = f + o; o += (size_t)NLAYER * 3 * DD * DD;
  f16* WoT   = f + o; o += (size_t)NLAYER * DD * DD;
  f16* W1T   = f + o; o += (size_t)NLAYER * FFD * DD;
  f16* W2T   = f + o; o += (size_t)NLAYER * DD * FFD;
  f16* R     = f + o; o += (size_t)NALL * FFD;     // alias: xpad | qkv+ao | mid
  f16* tmp16 = f + o; o += (size_t)NALL * DD;
  f16* h0f16 = f + o; o += (size_t)NALL * DD;
  f16* hmf16 = f + o; o += (size_t)NALL * DD;
  f16* pp    = f + o; o += (size_t)2 * NALL * DD;  // split-K partials (Wo, FF2)
  f16* outs16[4];
  for (int l = 0; l < 4; ++l) { outs16[l] = f + o; o += (size_t)NALL * DD; }

  f16* xpad = R;
  f16* qkv  = R;
  f16* ao   = R + (size_t)NALL * 3 * DD;
  f16* mid  = R;

  float* g32 = (float*)(f + o);
  size_t o2 = 0;
  float* bqkv = g32 + o2; o2 += (size_t)NLAYER * 3 * DD;
  float* part = g32 + o2; o2 += (size_t)NSPLIT * NB * 8 * DD;   // normsum partials
  float* invn = g32 + o2; o2 += NALL;

  // ---- weight prep (z-batched) ----
  transpose_cast_kernel<<<dim3(KPAD / 32, DD / 32, 1), 256, 0, stream>>>(
      fc1_w, fc1T, EMBD, DD, KPAD, 0, 0);
  transpose_cast_kernel<<<dim3(DD / 32, DD / 32, NLAYER), 256, 0, stream>>>(
      Wq, WqkvT, DD, DD, DD, (size_t)DD * DD, (size_t)3 * DD * DD);
  transpose_cast_kernel<<<dim3(DD / 32, DD / 32, NLAYER), 256, 0, stream>>>(
      Wk, WqkvT + (size_t)DD * DD, DD, DD, DD, (size_t)DD * DD, (size_t)3 * DD * DD);
  transpose_cast_kernel<<<dim3(DD / 32, DD / 32, NLAYER), 256, 0, stream>>>(
      Wv, WqkvT + (size_t)2 * DD * DD, DD, DD, DD, (size_t)DD * DD, (size_t)3 * DD * DD);
  transpose_cast_kernel<<<dim3(DD / 32, DD / 32, NLAYER), 256, 0, stream>>>(
      Wo, WoT, DD, DD, DD, (size_t)DD * DD, (size_t)DD * DD);
  transpose_cast_kernel<<<dim3(DD / 32, FFD / 32, NLAYER), 256, 0, stream>>>(
      W1, W1T, DD, FFD, DD, (size_t)DD * FFD, (size_t)FFD * DD);
  transpose_cast_kernel<<<dim3(FFD / 32, DD / 32, NLAYER), 256, 0, stream>>>(
      W2, W2T, FFD, DD, FFD, (size_t)FFD * DD, (size_t)DD * FFD);
  bias_concat_kernel<<<NLAYER, 256, 0, stream>>>(bq, bk, bv, bqkv);

  // ---- merged encoder over 6144 tokens ----
  castpad_kernel<<<NALL, 256, 0, stream>>>(ctx, asp, xpad);
  gemm_w512<KPAD, 1, 0><<<dim3(NALL / 128, DD / 128), 512, 0, stream>>>(
      xpad, fc1T, fc1_b, tmp16, DD);
  pos_ln16v<<<NALL, 192, 0, stream>>>(tmp16, pos, emb_g, emb_b, h0f16);

  const f16* hin16 = h0f16;
  for (int l = 0; l < NLAYER; ++l) {
    gemm_w512<DD, 1, 0><<<dim3(NALL / 128, (3 * DD) / 128), 512, 0, stream>>>(
        hin16, WqkvT + (size_t)l * 3 * DD * DD, bqkv + l * 3 * DD, qkv, 3 * DD);
    attn_all_kernel<<<2 * NB * HEADS, 256, 0, stream>>>(qkv, ao);
    gemm_w512<DD, 2, 0><<<dim3(NALL / 128, DD / 128, 2), 512, 0, stream>>>(
        ao, WoT + (size_t)l * DD * DD, bo + l * DD, pp, DD);
    add_ln16v<2><<<NALL, 192, 0, stream>>>(hin16, pp, pp + (size_t)NALL * DD,
                                           ln1g + l * DD, ln1b + l * DD, hmf16);
    gemm_w512<DD, 1, 1><<<dim3(NALL / 128, FFD / 128), 512, 0, stream>>>(
        hmf16, W1T + (size_t)l * FFD * DD, bf1 + l * FFD, mid, FFD);
    gemm_w512<FFD, 2, 0><<<dim3(NALL / 128, DD / 128, 2), 512, 0, stream>>>(
        mid, W2T + (size_t)l * DD * FFD, bf2 + l * DD, pp, DD);
    add_ln16v<2><<<NALL, 192, 0, stream>>>(hmf16, pp, pp + (size_t)NALL * DD,
                                           ln2g + l * DD, ln2b + l * DD, outs16[l]);
    hin16 = outs16[l];
  }

  OutsF16 o4;
  for (int i = 0; i < 4; ++i) o4.p[i] = outs16[i];
  invnorm16v<<<NALL, 192, 0, stream>>>(o4, invn);
  normsum16p<<<dim3(NB, 8, NSPLIT), 192, 0, stream>>>(o4, invn, part);
  final_dot2<<<NB, 256, 0, stream>>>(part, out);
}

// Round 17
// 799.192 us; speedup vs baseline: 1.8516x; 1.0687x over previous
//
#include <hip/hip_runtime.h>
#include <math.h>

typedef _Float16 f16;
typedef _Float16 h8 __attribute__((ext_vector_type(8)));
typedef _Float16 h4 __attribute__((ext_vector_type(4)));
typedef float f32x4 __attribute__((ext_vector_type(4)));

#define HEADS 12
#define DH 64
#define DD 768
#define FFD 3072
#define EMBD 300
#define KPAD 384
#define NLAYER 4
#define NB 16
#define NCTX 4096           // 16 * 256
#define NALL 6144           // 16*256 + 16*128
#define NSPLIT 8            // si-splits for normsum partials

// ---------------- block reductions ----------------
__device__ __forceinline__ float block_reduce_sum(float v, float* red) {
  #pragma unroll
  for (int o = 32; o; o >>= 1) v += __shfl_xor(v, o);
  const int wid = threadIdx.x >> 6;
  __syncthreads();
  if ((threadIdx.x & 63) == 0) red[wid] = v;
  __syncthreads();
  float r = red[0];
  #pragma unroll
  for (int w = 1; w < 4; ++w) r += red[w];
  return r;
}

__device__ __forceinline__ float block_reduce_sum3(float v, float* red) {
  #pragma unroll
  for (int o = 32; o; o >>= 1) v += __shfl_xor(v, o);
  const int wid = threadIdx.x >> 6;
  __syncthreads();
  if ((threadIdx.x & 63) == 0) red[wid] = v;
  __syncthreads();
  return red[0] + red[1] + red[2];
}

// ---------------- async global->LDS 16B ----------------
__device__ __forceinline__ void gload16(const f16* g, f16* lds) {
  __builtin_amdgcn_global_load_lds(
      (const __attribute__((address_space(1))) unsigned int*)g,
      (__attribute__((address_space(3))) unsigned int*)lds, 16, 0, 0);
}

// ---------------- weight transpose + cast (z-batched) ----------------
__launch_bounds__(256)
__global__ void transpose_cast_kernel(const float* __restrict__ W, f16* __restrict__ Wt,
                                      int K, int M, int Kpad,
                                      size_t srcStride, size_t dstStride) {
  W += (size_t)blockIdx.z * srcStride;
  Wt += (size_t)blockIdx.z * dstStride;
  __shared__ float t[32][33];
  const int k0 = blockIdx.x * 32, m0 = blockIdx.y * 32;
  const int c = threadIdx.x & 31, r8 = threadIdx.x >> 5;
  #pragma unroll
  for (int p = 0; p < 4; ++p) {
    const int k = k0 + r8 + p * 8;
    t[r8 + p * 8][c] = (k < K && m0 + c < M) ? W[(size_t)k * M + m0 + c] : 0.f;
  }
  __syncthreads();
  #pragma unroll
  for (int p = 0; p < 4; ++p) {
    const int m = m0 + r8 + p * 8;
    const int k = k0 + c;
    if (m < M && k < Kpad) Wt[(size_t)m * Kpad + k] = (f16)t[c][r8 + p * 8];
  }
}

__launch_bounds__(256)
__global__ void castpad_kernel(const float* __restrict__ ctx, const float* __restrict__ asp,
                               f16* __restrict__ xp) {
  const int tok = blockIdx.x;
  const float* src;
  int r;
  if (tok < NCTX) { src = ctx; r = tok; } else { src = asp; r = tok - NCTX; }
  for (int j = threadIdx.x; j < KPAD; j += 256)
    xp[(size_t)tok * KPAD + j] = (j < EMBD) ? (f16)src[(size_t)r * EMBD + j] : (f16)0.f;
}

__launch_bounds__(256)
__global__ void bias_concat_kernel(const float* __restrict__ bq, const float* __restrict__ bk,
                                   const float* __restrict__ bv, float* __restrict__ bqkv) {
  const int l = blockIdx.x;
  for (int j = threadIdx.x; j < DD; j += 256) {
    bqkv[l * 3 * DD + j] = bq[l * DD + j];
    bqkv[l * 3 * DD + DD + j] = bk[l * DD + j];
    bqkv[l * 3 * DD + 2 * DD + j] = bv[l * DD + j];
  }
}

// ======== 128x128 f16 GEMM, 512 threads / 8 waves (2Mx4N), 3-buffer 2-ahead ========
// Epilogue: wave-private LDS bounce (stride-40 rows, <=2-way banks) -> 16B
// coalesced h8 stores (4/thread) instead of 32 scalar f16 stores.
#define GBK 32

template<int K, int KSPLIT, int ACT>
__launch_bounds__(512, 6)
__global__ void gemm_w512(const f16* __restrict__ A, const f16* __restrict__ Bt,
                          const float* __restrict__ bias, f16* __restrict__ C, int M) {
  constexpr int KB = K / KSPLIT;
  constexpr int NSTEP = KB / GBK;
  static_assert(NSTEP >= 3, "need >=3 K-steps");
  __shared__ __align__(16) f16 smem[24576];    // 48 KB: As 3x4096 | Bs 3x4096
  f16* const AsB = smem;
  f16* const BsB = smem + 12288;
  const int tid = threadIdx.x, lane = tid & 63, wid = tid >> 6;
  const int wr = (wid >> 2) * 64, wc = (wid & 3) * 32;
  const int l15 = lane & 15, lg = lane >> 4;

  const int bm = blockIdx.x * 128;
  const int bn = blockIdx.y * 128;
  const int kb0 = (KSPLIT > 1) ? blockIdx.z * KB : 0;

  const int v0 = tid & 255, v1 = v0 + 256;
  const int r0 = v0 >> 2, s0 = v0 & 3;
  const int r1 = v1 >> 2, s1 = v1 & 3;
  const int gc0 = (s0 ^ ((r0 >> 1) & 3)) * 8;
  const int gc1 = (s1 ^ ((r1 >> 1) & 3)) * 8;
  const bool isA = (wid < 4);
  const f16* gsrc0 = isA ? A + (size_t)(bm + r0) * K + kb0 + gc0
                         : Bt + (size_t)(bn + r0) * K + kb0 + gc0;
  const f16* gsrc1 = isA ? A + (size_t)(bm + r1) * K + kb0 + gc1
                         : Bt + (size_t)(bn + r1) * K + kb0 + gc1;
  f16* dst0[3]; f16* dst1[3];
  #pragma unroll
  for (int b = 0; b < 3; ++b) {
    f16* base = isA ? AsB + b * 4096 : BsB + b * 4096;
    dst0[b] = base + ((wid & 3) * 64) * 8;
    dst1[b] = base + (256 + (wid & 3) * 64) * 8;
  }

  f32x4 acc[4][2] = {};

  gload16(gsrc0, dst0[0]);
  gload16(gsrc1, dst1[0]);
  gload16(gsrc0 + GBK, dst0[1]);
  gload16(gsrc1 + GBK, dst1[1]);

  int b3 = 0;
  for (int t = 0; t < NSTEP; ++t) {
    if (t + 1 < NSTEP) asm volatile("s_waitcnt vmcnt(2)" ::: "memory");
    else               asm volatile("s_waitcnt vmcnt(0)" ::: "memory");
    __builtin_amdgcn_s_barrier();
    if (t + 2 < NSTEP) {
      const int sn = (b3 + 2 >= 3) ? b3 - 1 : b3 + 2;
      gload16(gsrc0 + (t + 2) * GBK, dst0[sn]);
      gload16(gsrc1 + (t + 2) * GBK, dst1[sn]);
    }
    h8 af[4], bf[2];
    #pragma unroll
    for (int m = 0; m < 4; ++m) {
      const int row = wr + m * 16 + l15;
      af[m] = *(const h8*)&AsB[b3 * 4096 + (row * 4 + (lg ^ ((row >> 1) & 3))) * 8];
    }
    #pragma unroll
    for (int n = 0; n < 2; ++n) {
      const int row = wc + n * 16 + l15;
      bf[n] = *(const h8*)&BsB[b3 * 4096 + (row * 4 + (lg ^ ((row >> 1) & 3))) * 8];
    }
    #pragma unroll
    for (int m = 0; m < 4; ++m)
      #pragma unroll
      for (int n = 0; n < 2; ++n)
        acc[m][n] = __builtin_amdgcn_mfma_f32_16x16x32_f16(af[m], bf[n], acc[m][n], 0, 0, 0);
    b3 = (b3 + 1 >= 3) ? 0 : b3 + 1;
  }

  // ---- coalesced epilogue via wave-private LDS bounce ----
  __syncthreads();                       // retire all ds_reads before overwriting smem
  f16* const sc_ = smem + wid * 2560;    // 64 rows x stride 40 f16 (80B, 16B-aligned)
  #pragma unroll
  for (int m = 0; m < 4; ++m) {
    #pragma unroll
    for (int n = 0; n < 2; ++n) {
      #pragma unroll
      for (int r = 0; r < 4; ++r) {
        const int rl = m * 16 + lg * 4 + r;
        const int cl = n * 16 + l15;
        float vv = acc[m][n][r];
        if (KSPLIT == 1 || blockIdx.z == 0) vv += bias[bn + wc + cl];
        if (ACT == 1) {
          const float u = 1.5957691216057308f * (vv + 0.044715f * vv * vv * vv);
          vv = vv / (1.f + __expf(-u));
        }
        sc_[rl * 40 + cl] = (f16)vv;
      }
    }
  }
  // wave-private region: same-wave LDS ordering suffices, no barrier
  f16* Co = C + ((KSPLIT > 1) ? (size_t)blockIdx.z * NALL * M : (size_t)0);
  #pragma unroll
  for (int i = 0; i < 4; ++i) {
    const int chunk = lane + 64 * i;     // 256 chunks = 64 rows x 4 h8-cols
    const int rl = chunk >> 2, c8 = chunk & 3;
    *(h8*)&Co[(size_t)(bm + wr + rl) * M + bn + wc + c8 * 8] =
        *(const h8*)&sc_[rl * 40 + c8 * 8];
  }
}

// ---------------- MFMA attention: merged ctx+asp, one dispatch ----------------
#define KSTR 88
#define VSTR 264

template<int S>
__device__ __forceinline__ void attn_body(const f16* __restrict__ qkv, f16* __restrict__ ao,
                                          int tokoff, int bh,
                                          f16* __restrict__ Ks, f16* __restrict__ Vt,
                                          f16* __restrict__ Pl) {
  const int b = bh / HEADS, h = bh % HEADS;
  const int tid = threadIdx.x, lane = tid & 63, wid = tid >> 6;
  const int l15 = lane & 15, lg = lane >> 4;
  const size_t base = (size_t)(tokoff + b * S) * (3 * DD) + (size_t)h * DH;
  const f16* qg = qkv + base;
  const f16* kg = qkv + base + DD;
  const f16* vg = qkv + base + 2 * DD;

  for (int c = tid; c < S * 8; c += 256) {
    const int row = c >> 3, off = (c & 7) * 8;
    *(h8*)&Ks[row * KSTR + off] = *(const h8*)&kg[(size_t)row * (3 * DD) + off];
    const h8 vv = *(const h8*)&vg[(size_t)row * (3 * DD) + off];
    #pragma unroll
    for (int j = 0; j < 8; ++j) Vt[(off + j) * VSTR + row] = vv[j];
  }
  __syncthreads();

  for (int qt = wid; qt < S / 16; qt += 4) {
    const int q0 = qt * 16;
    h8 aq[2];
    #pragma unroll
    for (int s = 0; s < 2; ++s)
      aq[s] = *(const h8*)&qg[(size_t)(q0 + l15) * (3 * DD) + s * 32 + lg * 8];

    f32x4 sc[S / 16];
    #pragma unroll
    for (int kt = 0; kt < S / 16; ++kt) {
      f32x4 c = {};
      const h8 b0 = *(const h8*)&Ks[(kt * 16 + l15) * KSTR + lg * 8];
      const h8 b1 = *(const h8*)&Ks[(kt * 16 + l15) * KSTR + 32 + lg * 8];
      c = __builtin_amdgcn_mfma_f32_16x16x32_f16(aq[0], b0, c, 0, 0, 0);
      c = __builtin_amdgcn_mfma_f32_16x16x32_f16(aq[1], b1, c, 0, 0, 0);
      sc[kt] = c;
    }
    float mx[4], zz[4];
    #pragma unroll
    for (int r = 0; r < 4; ++r) {
      float m = -1e30f;
      #pragma unroll
      for (int kt = 0; kt < S / 16; ++kt) m = fmaxf(m, sc[kt][r]);
      #pragma unroll
      for (int o = 1; o < 16; o <<= 1) m = fmaxf(m, __shfl_xor(m, o));
      mx[r] = m; zz[r] = 0.f;
    }
    #pragma unroll
    for (int kt = 0; kt < S / 16; ++kt)
      #pragma unroll
      for (int r = 0; r < 4; ++r) {
        const float p = __expf((sc[kt][r] - mx[r]) * 0.125f);
        zz[r] += p;
        Pl[(wid * 16 + lg * 4 + r) * VSTR + kt * 16 + l15] = (f16)p;
      }
    #pragma unroll
    for (int r = 0; r < 4; ++r) {
      #pragma unroll
      for (int o = 1; o < 16; o <<= 1) zz[r] += __shfl_xor(zz[r], o);
      zz[r] = 1.f / zz[r];
    }
    // Pl is wave-private; same-wave LDS ordering, no barrier needed.
    f32x4 o4[4] = {};
    #pragma unroll
    for (int ks = 0; ks < S / 32; ++ks) {
      const h8 pa = *(const h8*)&Pl[(wid * 16 + l15) * VSTR + ks * 32 + lg * 8];
      #pragma unroll
      for (int n = 0; n < 4; ++n) {
        const h8 bv_ = *(const h8*)&Vt[(n * 16 + l15) * VSTR + ks * 32 + lg * 8];
        o4[n] = __builtin_amdgcn_mfma_f32_16x16x32_f16(pa, bv_, o4[n], 0, 0, 0);
      }
    }
    #pragma unroll
    for (int n = 0; n < 4; ++n)
      #pragma unroll
      for (int r = 0; r < 4; ++r) {
        const int row = q0 + lg * 4 + r;
        ao[(size_t)(tokoff + b * S + row) * DD + h * DH + n * 16 + l15] = (f16)(o4[n][r] * zz[r]);
      }
  }
}

__launch_bounds__(256)
__global__ void attn_all_kernel(const f16* __restrict__ qkv, f16* __restrict__ ao) {
  __shared__ __align__(16) f16 smem[56320];
  f16* Ks = smem;
  f16* Vt = smem + 22528;
  f16* Pl = smem + 22528 + 16896;
  const int bx = blockIdx.x;
  if (bx < NB * HEADS) attn_body<256>(qkv, ao, 0, bx, Ks, Vt, Pl);
  else                 attn_body<128>(qkv, ao, NCTX, bx - NB * HEADS, Ks, Vt, Pl);
}

// ---------------- vectorized LN kernels (192 threads, h4 = 8B/lane) ----------------
__launch_bounds__(192)
__global__ void pos_ln16v(const f16* __restrict__ tmp, const float* __restrict__ pos,
                          const float* __restrict__ g, const float* __restrict__ be,
                          f16* __restrict__ out) {
  __shared__ float red[3];
  const int tok = blockIdx.x;
  const int s = (tok < NCTX) ? (tok & 255) : (tok & 127);
  const size_t row = (size_t)tok * DD;
  const int j = threadIdx.x * 4;
  const h4 a = *(const h4*)&tmp[row + j];
  const float4 p = *(const float4*)&pos[(size_t)s * DD + j];
  float x[4] = { (float)a[0] + p.x, (float)a[1] + p.y, (float)a[2] + p.z, (float)a[3] + p.w };
  float sm = 0.f, ss = 0.f;
  #pragma unroll
  for (int i = 0; i < 4; ++i) { sm += x[i]; ss += x[i] * x[i]; }
  sm = block_reduce_sum3(sm, red);
  ss = block_reduce_sum3(ss, red);
  const float mean = sm * (1.f / DD);
  const float inv = rsqrtf(ss * (1.f / DD) - mean * mean + 1e-12f);
  const float4 gv = *(const float4*)&g[j];
  const float4 bv = *(const float4*)&be[j];
  h4 o;
  o[0] = (f16)((x[0] - mean) * inv * gv.x + bv.x);
  o[1] = (f16)((x[1] - mean) * inv * gv.y + bv.y);
  o[2] = (f16)((x[2] - mean) * inv * gv.z + bv.z);
  o[3] = (f16)((x[3] - mean) * inv * gv.w + bv.w);
  *(h4*)&out[row + j] = o;
}

template<int ND>
__launch_bounds__(192)
__global__ void add_ln16v(const f16* __restrict__ hin, const f16* __restrict__ d0,
                          const f16* __restrict__ d1,
                          const float* __restrict__ g, const float* __restrict__ be,
                          f16* __restrict__ out) {
  __shared__ float red[3];
  const size_t row = (size_t)blockIdx.x * DD;
  const int j = threadIdx.x * 4;
  const h4 a = *(const h4*)&hin[row + j];
  const h4 b = *(const h4*)&d0[row + j];
  h4 c = {};
  if (ND == 2) c = *(const h4*)&d1[row + j];
  float x[4]; float sm = 0.f, ss = 0.f;
  #pragma unroll
  for (int i = 0; i < 4; ++i) {
    float v = (float)a[i] + (float)b[i];
    if (ND == 2) v += (float)c[i];
    x[i] = v; sm += v; ss += v * v;
  }
  sm = block_reduce_sum3(sm, red);
  ss = block_reduce_sum3(ss, red);
  const float mean = sm * (1.f / DD);
  const float inv = rsqrtf(ss * (1.f / DD) - mean * mean + 1e-12f);
  const float4 gv = *(const float4*)&g[j];
  const float4 bv = *(const float4*)&be[j];
  h4 o;
  o[0] = (f16)((x[0] - mean) * inv * gv.x + bv.x);
  o[1] = (f16)((x[1] - mean) * inv * gv.y + bv.y);
  o[2] = (f16)((x[2] - mean) * inv * gv.z + bv.z);
  o[3] = (f16)((x[3] - mean) * inv * gv.w + bv.w);
  *(h4*)&out[row + j] = o;
}

// ---------------- final cosine reduction ----------------
struct OutsF16 { const f16* p[4]; };

__launch_bounds__(192)
__global__ void invnorm16v(OutsF16 o4, float* __restrict__ invn) {
  __shared__ float red[3];
  const size_t row = (size_t)blockIdx.x * DD;
  const int j = threadIdx.x * 4;
  float ss = 0.f;
  #pragma unroll
  for (int l = 0; l < 4; ++l) {
    const h4 v = *(const h4*)&o4.p[l][row + j];
    #pragma unroll
    for (int i = 0; i < 4; ++i) { const float f = (float)v[i]; ss += f * f; }
  }
  ss = block_reduce_sum3(ss, red);
  if (threadIdx.x == 0) invn[blockIdx.x] = 1.f / fmaxf(sqrtf(ss), 1e-8f);
}

__launch_bounds__(192)
__global__ void normsum16p(OutsF16 o4, const float* __restrict__ invn,
                           float* __restrict__ part) {
  const int b = blockIdx.x;
  const int y = blockIdx.y;            // pass*4 + l
  const int pass = y >> 2, l = y & 3;
  const int s = blockIdx.z;
  const int S = pass ? 128 : 256;
  const int tb = pass ? (NCTX + b * 128) : (b * 256);
  const int chunk = S / NSPLIT;
  const int si0 = s * chunk;
  const f16* __restrict__ src = o4.p[l];
  const int j = threadIdx.x * 4;
  float a0 = 0.f, a1 = 0.f, a2 = 0.f, a3 = 0.f;
  for (int si = si0; si < si0 + chunk; ++si) {
    const float w = invn[tb + si];
    const h4 v = *(const h4*)&src[(size_t)(tb + si) * DD + j];
    a0 = fmaf((float)v[0], w, a0);
    a1 = fmaf((float)v[1], w, a1);
    a2 = fmaf((float)v[2], w, a2);
    a3 = fmaf((float)v[3], w, a3);
  }
  float* dst = part + ((size_t)s * NB + b) * (8 * DD) + (size_t)y * DD + j;
  dst[0] = a0; dst[1] = a1; dst[2] = a2; dst[3] = a3;
}

__launch_bounds__(256)
__global__ void final_dot2(const float* __restrict__ part, float* __restrict__ out) {
  __shared__ float red[4];
  const int b = blockIdx.x;
  float sum = 0.f;
  #pragma unroll
  for (int i = 0; i < 12; ++i) {
    const int p = threadIdx.x + (i << 8);     // p in [0, 4*DD)
    float cs = 0.f, as_ = 0.f;
    #pragma unroll
    for (int s = 0; s < NSPLIT; ++s) {
      const float* base = part + ((size_t)s * NB + b) * (8 * DD);
      cs  += base[p];
      as_ += base[4 * DD + p];
    }
    sum = fmaf(as_, cs, sum);
  }
  sum = block_reduce_sum(sum, red);
  if (threadIdx.x == 0) out[b] = sum;
}

// ---------------- host orchestration ----------------
extern "C" void kernel_launch(void* const* d_in, const int* in_sizes, int n_in,
                              void* d_out, int out_size, void* d_ws, size_t ws_size,
                              hipStream_t stream) {
  (void)in_sizes; (void)n_in; (void)out_size; (void)ws_size;
  const float* ctx   = (const float*)d_in[0];
  const float* asp   = (const float*)d_in[1];
  const float* fc1_w = (const float*)d_in[2];
  const float* fc1_b = (const float*)d_in[3];
  const float* pos   = (const float*)d_in[4];
  const float* emb_g = (const float*)d_in[5];
  const float* emb_b = (const float*)d_in[6];
  const float* Wq    = (const float*)d_in[7];
  const float* bq    = (const float*)d_in[8];
  const float* Wk    = (const float*)d_in[9];
  const float* bk    = (const float*)d_in[10];
  const float* Wv    = (const float*)d_in[11];
  const float* bv    = (const float*)d_in[12];
  const float* Wo    = (const float*)d_in[13];
  const float* bo    = (const float*)d_in[14];
  const float* ln1g  = (const float*)d_in[15];
  const float* ln1b  = (const float*)d_in[16];
  const float* W1    = (const float*)d_in[17];
  const float* bf1   = (const float*)d_in[18];
  const float* W2    = (const float*)d_in[19];
  const float* bf2   = (const float*)d_in[20];
  const float* ln2g  = (const float*)d_in[21];
  const float* ln2b  = (const float*)d_in[22];
  float* out = (float*)d_out;

  // ---- workspace carving (all-f16 activations) ----
  f16* f = (f16*)d_ws;
  size_t o = 0;
  f16* fc1T  = f + o; o += (size_t)DD * KPAD;
  f16* WqkvT = f + o; o += (size_t)NLAYER * 3 * DD * DD;
  f16* WoT   = f + o; o += (size_t)NLAYER * DD * DD;
  f16* W1T   = f + o; o += (size_t)NLAYER * FFD * DD;
  f16* W2T   = f + o; o += (size_t)NLAYER * DD * FFD;
  f16* R     = f + o; o += (size_t)NALL * FFD;     // alias: xpad | qkv+ao | mid
  f16* tmp16 = f + o; o += (size_t)NALL * DD;
  f16* h0f16 = f + o; o += (size_t)NALL * DD;
  f16* hmf16 = f + o; o += (size_t)NALL * DD;
  f16* pp    = f + o; o += (size_t)2 * NALL * DD;  // split-K partials (Wo, FF2)
  f16* outs16[4];
  for (int l = 0; l < 4; ++l) { outs16[l] = f + o; o += (size_t)NALL * DD; }

  f16* xpad = R;
  f16* qkv  = R;
  f16* ao   = R + (size_t)NALL * 3 * DD;
  f16* mid  = R;

  float* g32 = (float*)(f + o);
  size_t o2 = 0;
  float* bqkv = g32 + o2; o2 += (size_t)NLAYER * 3 * DD;
  float* part = g32 + o2; o2 += (size_t)NSPLIT * NB * 8 * DD;   // normsum partials
  float* invn = g32 + o2; o2 += NALL;

  // ---- weight prep (z-batched) ----
  transpose_cast_kernel<<<dim3(KPAD / 32, DD / 32, 1), 256, 0, stream>>>(
      fc1_w, fc1T, EMBD, DD, KPAD, 0, 0);
  transpose_cast_kernel<<<dim3(DD / 32, DD / 32, NLAYER), 256, 0, stream>>>(
      Wq, WqkvT, DD, DD, DD, (size_t)DD * DD, (size_t)3 * DD * DD);
  transpose_cast_kernel<<<dim3(DD / 32, DD / 32, NLAYER), 256, 0, stream>>>(
      Wk, WqkvT + (size_t)DD * DD, DD, DD, DD, (size_t)DD * DD, (size_t)3 * DD * DD);
  transpose_cast_kernel<<<dim3(DD / 32, DD / 32, NLAYER), 256, 0, stream>>>(
      Wv, WqkvT + (size_t)2 * DD * DD, DD, DD, DD, (size_t)DD * DD, (size_t)3 * DD * DD);
  transpose_cast_kernel<<<dim3(DD / 32, DD / 32, NLAYER), 256, 0, stream>>>(
      Wo, WoT, DD, DD, DD, (size_t)DD * DD, (size_t)DD * DD);
  transpose_cast_kernel<<<dim3(DD / 32, FFD / 32, NLAYER), 256, 0, stream>>>(
      W1, W1T, DD, FFD, DD, (size_t)DD * FFD, (size_t)FFD * DD);
  transpose_cast_kernel<<<dim3(FFD / 32, DD / 32, NLAYER), 256, 0, stream>>>(
      W2, W2T, FFD, DD, FFD, (size_t)FFD * DD, (size_t)DD * FFD);
  bias_concat_kernel<<<NLAYER, 256, 0, stream>>>(bq, bk, bv, bqkv);

  // ---- merged encoder over 6144 tokens ----
  castpad_kernel<<<NALL, 256, 0, stream>>>(ctx, asp, xpad);
  gemm_w512<KPAD, 1, 0><<<dim3(NALL / 128, DD / 128), 512, 0, stream>>>(
      xpad, fc1T, fc1_b, tmp16, DD);
  pos_ln16v<<<NALL, 192, 0, stream>>>(tmp16, pos, emb_g, emb_b, h0f16);

  const f16* hin16 = h0f16;
  for (int l = 0; l < NLAYER; ++l) {
    gemm_w512<DD, 1, 0><<<dim3(NALL / 128, (3 * DD) / 128), 512, 0, stream>>>(
        hin16, WqkvT + (size_t)l * 3 * DD * DD, bqkv + l * 3 * DD, qkv, 3 * DD);
    attn_all_kernel<<<2 * NB * HEADS, 256, 0, stream>>>(qkv, ao);
    gemm_w512<DD, 2, 0><<<dim3(NALL / 128, DD / 128, 2), 512, 0, stream>>>(
        ao, WoT + (size_t)l * DD * DD, bo + l * DD, pp, DD);
    add_ln16v<2><<<NALL, 192, 0, stream>>>(hin16, pp, pp + (size_t)NALL * DD,
                                           ln1g + l * DD, ln1b + l * DD, hmf16);
    gemm_w512<DD, 1, 1><<<dim3(NALL / 128, FFD / 128), 512, 0, stream>>>(
        hmf16, W1T + (size_t)l * FFD * DD, bf1 + l * FFD, mid, FFD);
    gemm_w512<FFD, 2, 0><<<dim3(NALL / 128, DD / 128, 2), 512, 0, stream>>>(
        mid, W2T + (size_t)l * DD * FFD, bf2 + l * DD, pp, DD);
    add_ln16v<2><<<NALL, 192, 0, stream>>>(hmf16, pp, pp + (size_t)NALL * DD,
                                           ln2g + l * DD, ln2b + l * DD, outs16[l]);
    hin16 = outs16[l];
  }

  OutsF16 o4;
  for (int i = 0; i < 4; ++i) o4.p[i] = outs16[i];
  invnorm16v<<<NALL, 192, 0, stream>>>(o4, invn);
  normsum16p<<<dim3(NB, 8, NSPLIT), 192, 0, stream>>>(o4, invn, part);
  final_dot2<<<NB, 256, 0, stream>>>(part, out);
}